// Round 9
// baseline (1233.657 us; speedup 1.0000x reference)
//
#include <hip/hip_runtime.h>

#define N_NODES 50000
#define MPAD 50048            // 391 * 128, padded M for guard-free GEMM
#define N_EDGES 800000
#define H 256
#define K_CAT 512
#define G_BATCH 64
#define OUT_DIM 24

#define SCAN_BLK 256
#define NBLK ((N_NODES + SCAN_BLK - 1) / SCAN_BLK)   // 196

typedef __attribute__((ext_vector_type(8))) short short8;
typedef __attribute__((ext_vector_type(4))) float float4v;

// slot s holds feature F(s) = (s&0xC0)|((s&3)<<4)|((s>>2)&15); feature f lives at
// slot b(f) = (f&0xC0)|((f&15)<<2)|((f>>4)&3). Same permutation for u8 h8 and bf16 h.

__device__ __forceinline__ unsigned short f2bf(float f) {
    unsigned x = __float_as_uint(f);
    unsigned r = (x + 0x7FFFu + ((x >> 16) & 1u)) >> 16;   // RTNE
    return (unsigned short)r;
}
__device__ __forceinline__ float bf2f(unsigned short u) {
    return __uint_as_float(((unsigned)u) << 16);
}

__device__ __forceinline__ void async_copy16(void* lds, const void* g) {
    __builtin_amdgcn_global_load_lds(
        (const __attribute__((address_space(1))) unsigned int*)g,
        (__attribute__((address_space(3))) unsigned int*)lds, 16, 0, 0);
}

// ---------------- CSR build ----------------

__global__ void histo_kernel(const int* __restrict__ dst, int* __restrict__ deg,
                             int* __restrict__ epos) {
    int e = blockIdx.x * blockDim.x + threadIdx.x;
    if (e < N_EDGES) epos[e] = atomicAdd(&deg[dst[e]], 1);
}

__global__ void scan_block(const int* __restrict__ deg, int* __restrict__ rowptr,
                           int* __restrict__ blockSums) {
    __shared__ int s[SCAN_BLK];
    int idx = blockIdx.x * SCAN_BLK + threadIdx.x;
    int v = (idx < N_NODES) ? deg[idx] : 0;
    s[threadIdx.x] = v;
    __syncthreads();
    for (int off = 1; off < SCAN_BLK; off <<= 1) {
        int t = (threadIdx.x >= off) ? s[threadIdx.x - off] : 0;
        __syncthreads();
        s[threadIdx.x] += t;
        __syncthreads();
    }
    if (idx < N_NODES) rowptr[idx] = s[threadIdx.x] - v;
    if (threadIdx.x == SCAN_BLK - 1) blockSums[blockIdx.x] = s[threadIdx.x];
}

__global__ void scan_finish(int* __restrict__ rowptr, const int* __restrict__ blockSums) {
    __shared__ int s[SCAN_BLK];
    int t = threadIdx.x;
    int v = (t < NBLK) ? blockSums[t] : 0;
    s[t] = v;
    __syncthreads();
    for (int off = 1; off < SCAN_BLK; off <<= 1) {
        int tv = (t >= off) ? s[t - off] : 0;
        __syncthreads();
        s[t] += tv;
        __syncthreads();
    }
    int prefix = (blockIdx.x > 0) ? s[blockIdx.x - 1] : 0;
    int idx = blockIdx.x * SCAN_BLK + t;
    if (idx < N_NODES) rowptr[idx] += prefix;
    if (blockIdx.x == 0 && t == 0) rowptr[N_NODES] = s[NBLK - 1];
}

__global__ void fill_csr(const int* __restrict__ src, const int* __restrict__ dst,
                         const int* __restrict__ rowptr, const int* __restrict__ epos,
                         int* __restrict__ csr_src) {
    int e = blockIdx.x * blockDim.x + threadIdx.x;
    if (e >= N_EDGES) return;
    csr_src[rowptr[dst[e]] + epos[e]] = src[e];
}

// ---------------- weight prep (both k-halves permuted to slot order) ----------------

__global__ void prep_weights(const float* __restrict__ w_rel, const float* __restrict__ w_root,
                             unsigned short* __restrict__ WcatT) {
    int idx = blockIdx.x * blockDim.x + threadIdx.x;    // 6*512*256
    if (idx >= 6 * K_CAT * H) return;
    int n = idx & (H - 1);
    int k = (idx >> 8) & (K_CAT - 1);
    int l = idx >> 17;
    float v;
    if (k < H) {
        int f = (k & 0xC0) | ((k & 3) << 4) | ((k >> 2) & 15);
        v = w_rel[(size_t)l * H * H + f * H + n];
    } else {
        int kk = k - H;
        int f = (kk & 0xC0) | ((kk & 3) << 4) | ((kk >> 2) & 15);
        v = w_root[(size_t)l * H * H + f * H + n];
    }
    WcatT[(size_t)l * H * K_CAT + (size_t)n * K_CAT + k] = f2bf(v);
}

// ---------------- layer 1 (F_IN=3 -> H) ----------------

__global__ void agg3(const float* __restrict__ x, const int* __restrict__ rowptr,
                     const int* __restrict__ csr_src, float* __restrict__ agg) {
    int n = blockIdx.x * blockDim.x + threadIdx.x;
    if (n >= N_NODES) return;
    int beg = rowptr[n], end = rowptr[n + 1];
    float a0 = 0.f, a1 = 0.f, a2 = 0.f;
    for (int i = beg; i < end; ++i) {
        int s = csr_src[i];
        a0 += x[s * 3 + 0];
        a1 += x[s * 3 + 1];
        a2 += x[s * 3 + 2];
    }
    agg[n * 3 + 0] = a0;
    agg[n * 3 + 1] = a1;
    agg[n * 3 + 2] = a2;
}

// writes bf16 h in permuted slot order
__global__ void layer1_kernel(const float* __restrict__ x, const float* __restrict__ agg,
                              const float* __restrict__ wr, const float* __restrict__ wro,
                              const float* __restrict__ bias, unsigned short* __restrict__ cat) {
    int n = blockIdx.x;
    int f = threadIdx.x;
    float a0 = agg[n * 3 + 0], a1 = agg[n * 3 + 1], a2 = agg[n * 3 + 2];
    float x0 = x[n * 3 + 0], x1 = x[n * 3 + 1], x2 = x[n * 3 + 2];
    float v = bias[f];
    v += a0 * wr[0 * H + f] + a1 * wr[1 * H + f] + a2 * wr[2 * H + f];
    v += x0 * wro[0 * H + f] + x1 * wro[1 * H + f] + x2 * wro[2 * H + f];
    int bpos = (f & 0xC0) | ((f & 15) << 2) | ((f >> 4) & 3);
    cat[(size_t)n * K_CAT + H + bpos] = f2bf(fmaxf(v, 0.f));
}

// ---------------- per-slot column max of h (layer 1 only; later layers fuse in gemm) ----

__global__ __launch_bounds__(256) void colmax_h(const unsigned short* __restrict__ cat,
                                                float* __restrict__ cs) {
    int wave = threadIdx.x >> 6, lane = threadIdx.x & 63;
    int r0 = blockIdx.x * 512 + wave * 128;
    float m0 = 0.f, m1 = 0.f, m2 = 0.f, m3 = 0.f;
    for (int i = 0; i < 128; i++) {
        int r = r0 + i;
        if (r >= N_NODES) break;
        uint2 v = *(const uint2*)(cat + (size_t)r * K_CAT + H + lane * 4);
        m0 = fmaxf(m0, __uint_as_float(v.x << 16));
        m1 = fmaxf(m1, __uint_as_float(v.x & 0xffff0000u));
        m2 = fmaxf(m2, __uint_as_float(v.y << 16));
        m3 = fmaxf(m3, __uint_as_float(v.y & 0xffff0000u));
    }
    atomicMax((unsigned*)&cs[lane * 4 + 0], __float_as_uint(m0));
    atomicMax((unsigned*)&cs[lane * 4 + 1], __float_as_uint(m1));
    atomicMax((unsigned*)&cs[lane * 4 + 2], __float_as_uint(m2));
    atomicMax((unsigned*)&cs[lane * 4 + 3], __float_as_uint(m3));
}

// ---------------- quantize h (permuted bf16) -> u8 with per-slot scales ----------------

__global__ __launch_bounds__(256) void quant_u8(const unsigned short* __restrict__ cat,
                                                const float* __restrict__ cs,
                                                unsigned char* __restrict__ h8) {
    __shared__ float inv[H];
    int t = threadIdx.x;
    float c = cs[t];
    inv[t] = c > 0.f ? 255.f / c : 0.f;
    __syncthreads();
    int node = blockIdx.x * 4 + (t >> 6);
    if (node >= N_NODES) return;
    int s4 = (t & 63) * 4;
    uint2 v = *(const uint2*)(cat + (size_t)node * K_CAT + H + s4);
    float f0 = __uint_as_float(v.x << 16), f1 = __uint_as_float(v.x & 0xffff0000u);
    float f2 = __uint_as_float(v.y << 16), f3 = __uint_as_float(v.y & 0xffff0000u);
    unsigned q = (unsigned)(f0 * inv[s4] + 0.5f)
               | ((unsigned)(f1 * inv[s4 + 1] + 0.5f) << 8)
               | ((unsigned)(f2 * inv[s4 + 2] + 0.5f) << 16)
               | ((unsigned)(f3 * inv[s4 + 3] + 0.5f) << 24);
    *(unsigned*)(h8 + (size_t)node * H + s4) = q;
}

// ---------------- gather-aggregate, pure integer accumulation ----------------
// one wave per node; 4 sub-groups of 16 lanes = 4 edges per load; lane fl covers
// 16 bytes (slots fl*16..+15). u16-pair accumulators; dequant once at the end.

__global__ __launch_bounds__(256) void aggH(unsigned short* __restrict__ cat,
                                            const unsigned char* __restrict__ h8,
                                            const float* __restrict__ cs,
                                            const int* __restrict__ rowptr,
                                            const int* __restrict__ csr_src) {
    int gtid = blockIdx.x * blockDim.x + threadIdx.x;
    int node = gtid >> 6;
    if (node >= N_NODES) return;
    int lane = threadIdx.x & 63;
    int sub = lane >> 4;
    int fl = lane & 15;
    int beg = rowptr[node], end = rowptr[node + 1];
    unsigned short* o = cat + (size_t)node * K_CAT + fl * 16;

    if (beg >= end) {
        if (sub == 0) {
            uint4 z = make_uint4(0, 0, 0, 0);
            *(uint4*)o = z;
            *(uint4*)(o + 8) = z;
        }
        return;
    }

    unsigned accE[4] = {0, 0, 0, 0}, accO[4] = {0, 0, 0, 0};
    const unsigned char* base = h8 + fl * 16;
    int last = end - 1;

    for (int i0 = beg; i0 < end; i0 += 4) {
        int idx = i0 + sub;
        int s = csr_src[idx < end ? idx : last];
        uint4 q = *(const uint4*)(base + (size_t)s * H);
        if (idx >= end) { q.x = 0u; q.y = 0u; q.z = 0u; q.w = 0u; }
        accE[0] += q.x & 0x00FF00FFu;  accO[0] += (q.x >> 8) & 0x00FF00FFu;
        accE[1] += q.y & 0x00FF00FFu;  accO[1] += (q.y >> 8) & 0x00FF00FFu;
        accE[2] += q.z & 0x00FF00FFu;  accO[2] += (q.z >> 8) & 0x00FF00FFu;
        accE[3] += q.w & 0x00FF00FFu;  accO[3] += (q.w >> 8) & 0x00FF00FFu;
    }

#pragma unroll
    for (int j = 0; j < 4; j++) {
        accE[j] += __shfl_xor(accE[j], 16, 64);
        accE[j] += __shfl_xor(accE[j], 32, 64);
        accO[j] += __shfl_xor(accO[j], 16, 64);
        accO[j] += __shfl_xor(accO[j], 32, 64);
    }
    if (sub != 0) return;

    const float k = 1.f / 255.f;
    float4 c0 = *(const float4*)(cs + fl * 16);
    float4 c1 = *(const float4*)(cs + fl * 16 + 4);
    float4 c2 = *(const float4*)(cs + fl * 16 + 8);
    float4 c3 = *(const float4*)(cs + fl * 16 + 12);
    float v0  = (float)(accE[0] & 0xFFFFu) * (c0.x * k);
    float v1  = (float)(accO[0] & 0xFFFFu) * (c0.y * k);
    float v2  = (float)(accE[0] >> 16)     * (c0.z * k);
    float v3  = (float)(accO[0] >> 16)     * (c0.w * k);
    float v4  = (float)(accE[1] & 0xFFFFu) * (c1.x * k);
    float v5  = (float)(accO[1] & 0xFFFFu) * (c1.y * k);
    float v6  = (float)(accE[1] >> 16)     * (c1.z * k);
    float v7  = (float)(accO[1] >> 16)     * (c1.w * k);
    float v8  = (float)(accE[2] & 0xFFFFu) * (c2.x * k);
    float v9  = (float)(accO[2] & 0xFFFFu) * (c2.y * k);
    float v10 = (float)(accE[2] >> 16)     * (c2.z * k);
    float v11 = (float)(accO[2] >> 16)     * (c2.w * k);
    float v12 = (float)(accE[3] & 0xFFFFu) * (c3.x * k);
    float v13 = (float)(accO[3] & 0xFFFFu) * (c3.y * k);
    float v14 = (float)(accE[3] >> 16)     * (c3.z * k);
    float v15 = (float)(accO[3] >> 16)     * (c3.w * k);

    uint4 p0, p1;
    p0.x = (unsigned)f2bf(v0)  | ((unsigned)f2bf(v1) << 16);
    p0.y = (unsigned)f2bf(v2)  | ((unsigned)f2bf(v3) << 16);
    p0.z = (unsigned)f2bf(v4)  | ((unsigned)f2bf(v5) << 16);
    p0.w = (unsigned)f2bf(v6)  | ((unsigned)f2bf(v7) << 16);
    p1.x = (unsigned)f2bf(v8)  | ((unsigned)f2bf(v9) << 16);
    p1.y = (unsigned)f2bf(v10) | ((unsigned)f2bf(v11) << 16);
    p1.z = (unsigned)f2bf(v12) | ((unsigned)f2bf(v13) << 16);
    p1.w = (unsigned)f2bf(v14) | ((unsigned)f2bf(v15) << 16);
    *(uint4*)o = p0;
    *(uint4*)(o + 8) = p1;
}

// ---------------- MFMA GEMM, GBK=64; lean epilogue + fused col-max ----------------

#define GBM 128
#define GBN 128
#define GBK 64

__global__ __launch_bounds__(256) void gemm_mfma(
    const unsigned short* __restrict__ cat, const unsigned short* __restrict__ WcatT,
    const float* __restrict__ bias, unsigned short* __restrict__ catOut,
    float* __restrict__ csNext) {
    __shared__ unsigned short sA[GBM][GBK];   // 16 KB
    __shared__ unsigned short sB[GBN][GBK];   // 16 KB

    const int tid = threadIdx.x;
    const int wave = tid >> 6;
    const int lane = tid & 63;
    const int quad = lane >> 4;
    const int l16 = lane & 15;
    const int wm0 = (wave & 1) * 64;
    const int wn0 = (wave >> 1) * 64;
    const int m0 = blockIdx.x * GBM;
    const int n0 = blockIdx.y * GBN;

    const int rowoff = lane >> 3;
    const int schunk = ((lane & 7) ^ rowoff) * 8;   // shorts
    const unsigned short* Asrc[4];
    const unsigned short* Bsrc[4];
#pragma unroll
    for (int j = 0; j < 4; j++) {
        int q = wave * 4 + j;
        Asrc[j] = cat + (size_t)(m0 + q * 8 + rowoff) * K_CAT + schunk;
        Bsrc[j] = WcatT + (size_t)(n0 + q * 8 + rowoff) * K_CAT + schunk;
    }

    const int sw = l16 & 7;
    const int ca0 = (quad ^ sw) * 8;
    const int ca1 = ((4 + quad) ^ sw) * 8;

    float4v acc[4][4] = {};

    for (int kk = 0; kk < K_CAT; kk += GBK) {
#pragma unroll
        for (int j = 0; j < 4; j++) {
            char* da = (char*)sA + (wave * 4 + j) * 1024;
            char* db = (char*)sB + (wave * 4 + j) * 1024;
            async_copy16(da, Asrc[j] + kk);
            async_copy16(db, Bsrc[j] + kk);
        }
        __syncthreads();

        short8 a[4][2], b[4][2];
#pragma unroll
        for (int i = 0; i < 4; i++) {
            const unsigned short* ra = &sA[wm0 + i * 16 + l16][0];
            const unsigned short* rb = &sB[wn0 + i * 16 + l16][0];
            a[i][0] = *(const short8*)(ra + ca0);
            a[i][1] = *(const short8*)(ra + ca1);
            b[i][0] = *(const short8*)(rb + ca0);
            b[i][1] = *(const short8*)(rb + ca1);
        }
#pragma unroll
        for (int sub = 0; sub < 2; sub++)
#pragma unroll
            for (int mi = 0; mi < 4; mi++)
#pragma unroll
                for (int ni = 0; ni < 4; ni++)
                    acc[mi][ni] = __builtin_amdgcn_mfma_f32_16x16x32_bf16(
                        a[mi][sub], b[ni][sub], acc[mi][ni], 0, 0, 0);
        __syncthreads();
    }

    // epilogue: bias+relu; permuted-contiguous bf16 store (u64); running col-max
    const int colbase = n0 + wn0;
    float bcol[4];
#pragma unroll
    for (int ni = 0; ni < 4; ni++) bcol[ni] = bias[colbase + ni * 16 + l16];
    float cm[4] = {0.f, 0.f, 0.f, 0.f};

#pragma unroll
    for (int mi = 0; mi < 4; mi++) {
        int rowb = m0 + wm0 + mi * 16 + quad * 4;
#pragma unroll
        for (int r = 0; r < 4; r++) {
            int row = rowb + r;
            float v0 = fmaxf(acc[mi][0][r] + bcol[0], 0.f);
            float v1 = fmaxf(acc[mi][1][r] + bcol[1], 0.f);
            float v2 = fmaxf(acc[mi][2][r] + bcol[2], 0.f);
            float v3 = fmaxf(acc[mi][3][r] + bcol[3], 0.f);
            uint2 p;
            p.x = (unsigned)f2bf(v0) | ((unsigned)f2bf(v1) << 16);
            p.y = (unsigned)f2bf(v2) | ((unsigned)f2bf(v3) << 16);
            *(uint2*)(catOut + (size_t)row * K_CAT + H + colbase + l16 * 4) = p;
            bool val = row < N_NODES;
            cm[0] = fmaxf(cm[0], val ? v0 : 0.f);
            cm[1] = fmaxf(cm[1], val ? v1 : 0.f);
            cm[2] = fmaxf(cm[2], val ? v2 : 0.f);
            cm[3] = fmaxf(cm[3], val ? v3 : 0.f);
        }
    }
#pragma unroll
    for (int ni = 0; ni < 4; ni++) {
        cm[ni] = fmaxf(cm[ni], __shfl_xor(cm[ni], 16, 64));
        cm[ni] = fmaxf(cm[ni], __shfl_xor(cm[ni], 32, 64));
    }
    if (quad == 0) {
#pragma unroll
        for (int ni = 0; ni < 4; ni++)
            atomicMax((unsigned*)&csNext[colbase + l16 * 4 + ni], __float_as_uint(cm[ni]));
    }
}

// ---------------- pooling ----------------

__device__ __forceinline__ int lowerBound(const int* __restrict__ batch, int val) {
    int lo = 0, hi = N_NODES;
    while (lo < hi) {
        int mid = (lo + hi) >> 1;
        if (batch[mid] < val) lo = mid + 1; else hi = mid;
    }
    return lo;
}

__global__ void pool_partial(const unsigned short* __restrict__ cat, const int* __restrict__ batch,
                             float* __restrict__ pooled) {
    int g = blockIdx.x;
    int seg = blockIdx.y;
    int f = threadIdx.x;
    int start = lowerBound(batch, g);
    int end = lowerBound(batch, g + 1);
    int len = end - start;
    int s0 = start + (int)((long long)len * seg / 8);
    int s1 = start + (int)((long long)len * (seg + 1) / 8);
    float sum = 0.f;
    for (int n = s0; n < s1; ++n)
        sum += bf2f(cat[(size_t)n * K_CAT + H + f]);
    if (s1 > s0)
        atomicAdd(&pooled[g * H + f], sum);
}

__global__ void head_kernel(const float* __restrict__ pooled, const int* __restrict__ batch,
                            const float* __restrict__ w_out, const float* __restrict__ b_out,
                            float* __restrict__ out) {
    int g = blockIdx.x;
    int o = threadIdx.x;
    int start = lowerBound(batch, g);
    int end = lowerBound(batch, g + 1);
    float cnt = fmaxf((float)(end - start), 1.f);
    float sum = 0.f;
    for (int b = 0; b < H; ++b) {
        int f = (b & 0xC0) | ((b & 3) << 4) | ((b >> 2) & 15);
        sum += pooled[g * H + b] * w_out[f * OUT_DIM + o];
    }
    out[g * OUT_DIM + o] = b_out[o] + sum / cnt;
}

// ---------------- launch ----------------

extern "C" void kernel_launch(void* const* d_in, const int* in_sizes, int n_in,
                              void* d_out, int out_size, void* d_ws, size_t ws_size,
                              hipStream_t stream) {
    const float* x      = (const float*)d_in[0];
    const int*   ei     = (const int*)d_in[1];
    const int*   batch  = (const int*)d_in[2];
    const float* w_rel1 = (const float*)d_in[3];
    const float* w_root1= (const float*)d_in[4];
    const float* b1     = (const float*)d_in[5];
    const float* w_rel  = (const float*)d_in[6];
    const float* w_root = (const float*)d_in[7];
    const float* b      = (const float*)d_in[8];
    const float* w_out  = (const float*)d_in[9];
    const float* b_out  = (const float*)d_in[10];
    float* out = (float*)d_out;

    const int* src = ei;
    const int* dst = ei + N_EDGES;

    unsigned short* catA  = (unsigned short*)d_ws;                       // MPAD*512 bf16
    unsigned short* catB  = catA + (size_t)MPAD * K_CAT;                 // MPAD*512 bf16
    unsigned short* WcatT = catB + (size_t)MPAD * K_CAT;                 // 6*256*512 bf16
    float* agg3buf = (float*)(WcatT + (size_t)6 * H * K_CAT);            // N*4 f32
    float* pooled  = agg3buf + (size_t)N_NODES * 4;                      // G*H f32
    float* csAll   = pooled + G_BATCH * H;                               // 8*256 f32
    unsigned char* h8 = (unsigned char*)(csAll + 8 * H);                 // N*256 u8 (16B-aligned)
    int* rowptr    = (int*)(h8 + (size_t)N_NODES * H);                   // N+1
    int* degcur    = rowptr + (N_NODES + 1);                             // N
    int* blockSums = degcur + N_NODES;                                   // 256
    int* csr_src   = blockSums + SCAN_BLK;                               // E
    int* epos      = csr_src + N_EDGES;                                  // E

    // ---- build CSR ----
    hipMemsetAsync(degcur, 0, N_NODES * sizeof(int), stream);
    hipMemsetAsync(csAll, 0, 8 * H * sizeof(float), stream);
    histo_kernel<<<(N_EDGES + 255) / 256, 256, 0, stream>>>(dst, degcur, epos);
    scan_block<<<NBLK, SCAN_BLK, 0, stream>>>(degcur, rowptr, blockSums);
    scan_finish<<<NBLK, SCAN_BLK, 0, stream>>>(rowptr, blockSums);
    fill_csr<<<(N_EDGES + 255) / 256, 256, 0, stream>>>(src, dst, rowptr, epos, csr_src);

    // ---- weights -> bf16 transposed cat (both halves slot-permuted) ----
    prep_weights<<<(6 * K_CAT * H + 255) / 256, 256, 0, stream>>>(w_rel, w_root, WcatT);

    // ---- layer 1 (3 -> 256), fp32, permuted bf16 h ----
    agg3<<<(N_NODES + 255) / 256, 256, 0, stream>>>(x, rowptr, csr_src, agg3buf);
    layer1_kernel<<<N_NODES, H, 0, stream>>>(x, agg3buf, w_rel1, w_root1, b1, catA);
    colmax_h<<<(N_NODES + 511) / 512, 256, 0, stream>>>(catA, csAll + 1 * H);

    // ---- layers 2..7: quant -> int8 gather-agg -> bf16 MFMA (+ col-max for next) ----
    unsigned short* cur = catA;
    unsigned short* nxt = catB;
    for (int l = 1; l <= 6; ++l) {
        quant_u8<<<(N_NODES + 3) / 4, 256, 0, stream>>>(cur, csAll + (size_t)l * H, h8);
        aggH<<<(N_NODES * 64 + 255) / 256, 256, 0, stream>>>(cur, h8, csAll + (size_t)l * H,
                                                             rowptr, csr_src);
        dim3 grid(MPAD / GBM, H / GBN);
        gemm_mfma<<<grid, 256, 0, stream>>>(cur, WcatT + (size_t)(l - 1) * H * K_CAT,
                                            b + (size_t)(l - 1) * H, nxt,
                                            csAll + (size_t)(l + 1) * H);
        unsigned short* t = cur; cur = nxt; nxt = t;
    }

    // ---- global mean pool + head ----
    hipMemsetAsync(pooled, 0, G_BATCH * H * sizeof(float), stream);
    pool_partial<<<dim3(G_BATCH, 8), 256, 0, stream>>>(cur, batch, pooled);
    head_kernel<<<G_BATCH, OUT_DIM, 0, stream>>>(pooled, batch, w_out, b_out, out);
}

// Round 11
// 776.332 us; speedup vs baseline: 1.5891x; 1.5891x over previous
//
#include <hip/hip_runtime.h>

#define N_NODES 50000
#define MPAD 50048            // 391 * 128, padded M for guard-free GEMM
#define N_EDGES 800000
#define H 256
#define K_CAT 512
#define G_BATCH 64
#define OUT_DIM 24

#define SCAN_BLK 256
#define NBLK ((N_NODES + SCAN_BLK - 1) / SCAN_BLK)   // 196
#define MAXSLOT 782           // max partial-max slots (gemm: 391*2)

typedef __attribute__((ext_vector_type(8))) short short8;
typedef __attribute__((ext_vector_type(4))) float float4v;

// slot s holds feature F(s) = (s&0xC0)|((s&3)<<4)|((s>>2)&15); feature f lives at
// slot b(f) = (f&0xC0)|((f&15)<<2)|((f>>4)&3). Same permutation for u8 h8 and bf16 h.
// cs[] is indexed by SLOT. The gemm epilogue stores v_ni (logical col colbase+ni*16+l16)
// at slot colbase + l16*4 + ni, so its col-max partial must use w = l16*4 + ni.

__device__ __forceinline__ unsigned short f2bf(float f) {
    unsigned x = __float_as_uint(f);
    unsigned r = (x + 0x7FFFu + ((x >> 16) & 1u)) >> 16;   // RTNE
    return (unsigned short)r;
}
__device__ __forceinline__ float bf2f(unsigned short u) {
    return __uint_as_float(((unsigned)u) << 16);
}

__device__ __forceinline__ void async_copy16(void* lds, const void* g) {
    __builtin_amdgcn_global_load_lds(
        (const __attribute__((address_space(1))) unsigned int*)g,
        (__attribute__((address_space(3))) unsigned int*)lds, 16, 0, 0);
}

// ---------------- CSR build ----------------

__global__ void histo_kernel(const int* __restrict__ dst, int* __restrict__ deg,
                             int* __restrict__ epos) {
    int e = blockIdx.x * blockDim.x + threadIdx.x;
    if (e < N_EDGES) epos[e] = atomicAdd(&deg[dst[e]], 1);
}

__global__ void scan_block(const int* __restrict__ deg, int* __restrict__ rowptr,
                           int* __restrict__ blockSums) {
    __shared__ int s[SCAN_BLK];
    int idx = blockIdx.x * SCAN_BLK + threadIdx.x;
    int v = (idx < N_NODES) ? deg[idx] : 0;
    s[threadIdx.x] = v;
    __syncthreads();
    for (int off = 1; off < SCAN_BLK; off <<= 1) {
        int t = (threadIdx.x >= off) ? s[threadIdx.x - off] : 0;
        __syncthreads();
        s[threadIdx.x] += t;
        __syncthreads();
    }
    if (idx < N_NODES) rowptr[idx] = s[threadIdx.x] - v;
    if (threadIdx.x == SCAN_BLK - 1) blockSums[blockIdx.x] = s[threadIdx.x];
}

__global__ void scan_finish(int* __restrict__ rowptr, const int* __restrict__ blockSums) {
    __shared__ int s[SCAN_BLK];
    int t = threadIdx.x;
    int v = (t < NBLK) ? blockSums[t] : 0;
    s[t] = v;
    __syncthreads();
    for (int off = 1; off < SCAN_BLK; off <<= 1) {
        int tv = (t >= off) ? s[t - off] : 0;
        __syncthreads();
        s[t] += tv;
        __syncthreads();
    }
    int prefix = (blockIdx.x > 0) ? s[blockIdx.x - 1] : 0;
    int idx = blockIdx.x * SCAN_BLK + t;
    if (idx < N_NODES) rowptr[idx] += prefix;
    if (blockIdx.x == 0 && t == 0) rowptr[N_NODES] = s[NBLK - 1];
}

__global__ void fill_csr(const int* __restrict__ src, const int* __restrict__ dst,
                         const int* __restrict__ rowptr, const int* __restrict__ epos,
                         int* __restrict__ csr_src) {
    int e = blockIdx.x * blockDim.x + threadIdx.x;
    if (e >= N_EDGES) return;
    csr_src[rowptr[dst[e]] + epos[e]] = src[e];
}

// ---------------- weight prep (both k-halves permuted to slot order) ----------------

__global__ void prep_weights(const float* __restrict__ w_rel, const float* __restrict__ w_root,
                             unsigned short* __restrict__ WcatT) {
    int idx = blockIdx.x * blockDim.x + threadIdx.x;    // 6*512*256
    if (idx >= 6 * K_CAT * H) return;
    int n = idx & (H - 1);
    int k = (idx >> 8) & (K_CAT - 1);
    int l = idx >> 17;
    float v;
    if (k < H) {
        int f = (k & 0xC0) | ((k & 3) << 4) | ((k >> 2) & 15);
        v = w_rel[(size_t)l * H * H + f * H + n];
    } else {
        int kk = k - H;
        int f = (kk & 0xC0) | ((kk & 3) << 4) | ((kk >> 2) & 15);
        v = w_root[(size_t)l * H * H + f * H + n];
    }
    WcatT[(size_t)l * H * K_CAT + (size_t)n * K_CAT + k] = f2bf(v);
}

// ---------------- layer 1 (F_IN=3 -> H) ----------------

__global__ void agg3(const float* __restrict__ x, const int* __restrict__ rowptr,
                     const int* __restrict__ csr_src, float* __restrict__ agg) {
    int n = blockIdx.x * blockDim.x + threadIdx.x;
    if (n >= N_NODES) return;
    int beg = rowptr[n], end = rowptr[n + 1];
    float a0 = 0.f, a1 = 0.f, a2 = 0.f;
    for (int i = beg; i < end; ++i) {
        int s = csr_src[i];
        a0 += x[s * 3 + 0];
        a1 += x[s * 3 + 1];
        a2 += x[s * 3 + 2];
    }
    agg[n * 3 + 0] = a0;
    agg[n * 3 + 1] = a1;
    agg[n * 3 + 2] = a2;
}

// writes bf16 h in permuted slot order
__global__ void layer1_kernel(const float* __restrict__ x, const float* __restrict__ agg,
                              const float* __restrict__ wr, const float* __restrict__ wro,
                              const float* __restrict__ bias, unsigned short* __restrict__ cat) {
    int n = blockIdx.x;
    int f = threadIdx.x;
    float a0 = agg[n * 3 + 0], a1 = agg[n * 3 + 1], a2 = agg[n * 3 + 2];
    float x0 = x[n * 3 + 0], x1 = x[n * 3 + 1], x2 = x[n * 3 + 2];
    float v = bias[f];
    v += a0 * wr[0 * H + f] + a1 * wr[1 * H + f] + a2 * wr[2 * H + f];
    v += x0 * wro[0 * H + f] + x1 * wro[1 * H + f] + x2 * wro[2 * H + f];
    int bpos = (f & 0xC0) | ((f & 15) << 2) | ((f >> 4) & 3);
    cat[(size_t)n * K_CAT + H + bpos] = f2bf(fmaxf(v, 0.f));
}

// ---------------- per-slot column max partials of h (layer 1; atomic-free) ----------------
// slot = blockIdx.x*4 + wave covers rows slot*128..+127; lane covers slots lane*4..+3.

__global__ __launch_bounds__(256) void colmax_part(const unsigned short* __restrict__ cat,
                                                   float* __restrict__ partial) {
    int wave = threadIdx.x >> 6, lane = threadIdx.x & 63;
    int slot = blockIdx.x * 4 + wave;
    int r0 = slot * 128;
    float m0 = 0.f, m1 = 0.f, m2 = 0.f, m3 = 0.f;
    for (int i = 0; i < 128; i++) {
        int r = r0 + i;
        if (r >= N_NODES) break;
        uint2 v = *(const uint2*)(cat + (size_t)r * K_CAT + H + lane * 4);
        m0 = fmaxf(m0, __uint_as_float(v.x << 16));
        m1 = fmaxf(m1, __uint_as_float(v.x & 0xffff0000u));
        m2 = fmaxf(m2, __uint_as_float(v.y << 16));
        m3 = fmaxf(m3, __uint_as_float(v.y & 0xffff0000u));
    }
    int cg = lane >> 4;
    int w = (lane * 4) & 63;
    float* p = partial + ((size_t)cg * MAXSLOT + slot) * 64 + w;
    p[0] = m0; p[1] = m1; p[2] = m2; p[3] = m3;
}

// ---------------- fold partial col-maxes -> cs[256] (grid = 4 cgs, block = 1024) ------

__global__ __launch_bounds__(1024) void reduce_cols(const float* __restrict__ partial,
                                                    int nslots, float* __restrict__ cs) {
    __shared__ float red[1024];
    int cg = blockIdx.x;
    int tid = threadIdx.x;
    int j = tid >> 6, w = tid & 63;
    float m = 0.f;
    for (int s = j; s < nslots; s += 16)
        m = fmaxf(m, partial[((size_t)cg * MAXSLOT + s) * 64 + w]);
    red[tid] = m;
    __syncthreads();
    for (int st = 8; st >= 1; st >>= 1) {
        if (j < st) red[tid] = fmaxf(red[tid], red[tid + st * 64]);
        __syncthreads();
    }
    if (j == 0) cs[cg * 64 + w] = red[tid];
}

// ---------------- quantize h (permuted bf16) -> u8 with per-slot scales ----------------

__global__ __launch_bounds__(256) void quant_u8(const unsigned short* __restrict__ cat,
                                                const float* __restrict__ cs,
                                                unsigned char* __restrict__ h8) {
    __shared__ float inv[H];
    int t = threadIdx.x;
    float c = cs[t];
    inv[t] = c > 0.f ? 255.f / c : 0.f;
    __syncthreads();
    int node = blockIdx.x * 4 + (t >> 6);
    if (node >= N_NODES) return;
    int s4 = (t & 63) * 4;
    uint2 v = *(const uint2*)(cat + (size_t)node * K_CAT + H + s4);
    float f0 = __uint_as_float(v.x << 16), f1 = __uint_as_float(v.x & 0xffff0000u);
    float f2 = __uint_as_float(v.y << 16), f3 = __uint_as_float(v.y & 0xffff0000u);
    unsigned q = (unsigned)(f0 * inv[s4] + 0.5f)
               | ((unsigned)(f1 * inv[s4 + 1] + 0.5f) << 8)
               | ((unsigned)(f2 * inv[s4 + 2] + 0.5f) << 16)
               | ((unsigned)(f3 * inv[s4 + 3] + 0.5f) << 24);
    *(unsigned*)(h8 + (size_t)node * H + s4) = q;
}

// ---------------- gather-aggregate, pure integer accumulation ----------------

__global__ __launch_bounds__(256) void aggH(unsigned short* __restrict__ cat,
                                            const unsigned char* __restrict__ h8,
                                            const float* __restrict__ cs,
                                            const int* __restrict__ rowptr,
                                            const int* __restrict__ csr_src) {
    int gtid = blockIdx.x * blockDim.x + threadIdx.x;
    int node = gtid >> 6;
    if (node >= N_NODES) return;
    int lane = threadIdx.x & 63;
    int sub = lane >> 4;
    int fl = lane & 15;
    int beg = rowptr[node], end = rowptr[node + 1];
    unsigned short* o = cat + (size_t)node * K_CAT + fl * 16;

    if (beg >= end) {
        if (sub == 0) {
            uint4 z = make_uint4(0, 0, 0, 0);
            *(uint4*)o = z;
            *(uint4*)(o + 8) = z;
        }
        return;
    }

    unsigned accE[4] = {0, 0, 0, 0}, accO[4] = {0, 0, 0, 0};
    const unsigned char* base = h8 + fl * 16;
    int last = end - 1;

    for (int i0 = beg; i0 < end; i0 += 4) {
        int idx = i0 + sub;
        int s = csr_src[idx < end ? idx : last];
        uint4 q = *(const uint4*)(base + (size_t)s * H);
        if (idx >= end) { q.x = 0u; q.y = 0u; q.z = 0u; q.w = 0u; }
        accE[0] += q.x & 0x00FF00FFu;  accO[0] += (q.x >> 8) & 0x00FF00FFu;
        accE[1] += q.y & 0x00FF00FFu;  accO[1] += (q.y >> 8) & 0x00FF00FFu;
        accE[2] += q.z & 0x00FF00FFu;  accO[2] += (q.z >> 8) & 0x00FF00FFu;
        accE[3] += q.w & 0x00FF00FFu;  accO[3] += (q.w >> 8) & 0x00FF00FFu;
    }

#pragma unroll
    for (int j = 0; j < 4; j++) {
        accE[j] += __shfl_xor(accE[j], 16, 64);
        accE[j] += __shfl_xor(accE[j], 32, 64);
        accO[j] += __shfl_xor(accO[j], 16, 64);
        accO[j] += __shfl_xor(accO[j], 32, 64);
    }
    if (sub != 0) return;

    const float k = 1.f / 255.f;
    float4 c0 = *(const float4*)(cs + fl * 16);
    float4 c1 = *(const float4*)(cs + fl * 16 + 4);
    float4 c2 = *(const float4*)(cs + fl * 16 + 8);
    float4 c3 = *(const float4*)(cs + fl * 16 + 12);
    float v0  = (float)(accE[0] & 0xFFFFu) * (c0.x * k);
    float v1  = (float)(accO[0] & 0xFFFFu) * (c0.y * k);
    float v2  = (float)(accE[0] >> 16)     * (c0.z * k);
    float v3  = (float)(accO[0] >> 16)     * (c0.w * k);
    float v4  = (float)(accE[1] & 0xFFFFu) * (c1.x * k);
    float v5  = (float)(accO[1] & 0xFFFFu) * (c1.y * k);
    float v6  = (float)(accE[1] >> 16)     * (c1.z * k);
    float v7  = (float)(accO[1] >> 16)     * (c1.w * k);
    float v8  = (float)(accE[2] & 0xFFFFu) * (c2.x * k);
    float v9  = (float)(accO[2] & 0xFFFFu) * (c2.y * k);
    float v10 = (float)(accE[2] >> 16)     * (c2.z * k);
    float v11 = (float)(accO[2] >> 16)     * (c2.w * k);
    float v12 = (float)(accE[3] & 0xFFFFu) * (c3.x * k);
    float v13 = (float)(accO[3] & 0xFFFFu) * (c3.y * k);
    float v14 = (float)(accE[3] >> 16)     * (c3.z * k);
    float v15 = (float)(accO[3] >> 16)     * (c3.w * k);

    uint4 p0, p1;
    p0.x = (unsigned)f2bf(v0)  | ((unsigned)f2bf(v1) << 16);
    p0.y = (unsigned)f2bf(v2)  | ((unsigned)f2bf(v3) << 16);
    p0.z = (unsigned)f2bf(v4)  | ((unsigned)f2bf(v5) << 16);
    p0.w = (unsigned)f2bf(v6)  | ((unsigned)f2bf(v7) << 16);
    p1.x = (unsigned)f2bf(v8)  | ((unsigned)f2bf(v9) << 16);
    p1.y = (unsigned)f2bf(v10) | ((unsigned)f2bf(v11) << 16);
    p1.z = (unsigned)f2bf(v12) | ((unsigned)f2bf(v13) << 16);
    p1.w = (unsigned)f2bf(v14) | ((unsigned)f2bf(v15) << 16);
    *(uint4*)o = p0;
    *(uint4*)(o + 8) = p1;
}

// ---------------- MFMA GEMM, GBK=64; lean epilogue + atomic-free col-max partials ------

#define GBM 128
#define GBN 128
#define GBK 64

__global__ __launch_bounds__(256) void gemm_mfma(
    const unsigned short* __restrict__ cat, const unsigned short* __restrict__ WcatT,
    const float* __restrict__ bias, unsigned short* __restrict__ catOut,
    float* __restrict__ partial) {
    __shared__ unsigned short sA[GBM][GBK];   // 16 KB
    __shared__ unsigned short sB[GBN][GBK];   // 16 KB

    const int tid = threadIdx.x;
    const int wave = tid >> 6;
    const int lane = tid & 63;
    const int quad = lane >> 4;
    const int l16 = lane & 15;
    const int wm0 = (wave & 1) * 64;
    const int wn0 = (wave >> 1) * 64;
    const int m0 = blockIdx.x * GBM;
    const int n0 = blockIdx.y * GBN;

    const int rowoff = lane >> 3;
    const int schunk = ((lane & 7) ^ rowoff) * 8;   // shorts
    const unsigned short* Asrc[4];
    const unsigned short* Bsrc[4];
#pragma unroll
    for (int j = 0; j < 4; j++) {
        int q = wave * 4 + j;
        Asrc[j] = cat + (size_t)(m0 + q * 8 + rowoff) * K_CAT + schunk;
        Bsrc[j] = WcatT + (size_t)(n0 + q * 8 + rowoff) * K_CAT + schunk;
    }

    const int sw = l16 & 7;
    const int ca0 = (quad ^ sw) * 8;
    const int ca1 = ((4 + quad) ^ sw) * 8;

    float4v acc[4][4] = {};

    for (int kk = 0; kk < K_CAT; kk += GBK) {
#pragma unroll
        for (int j = 0; j < 4; j++) {
            char* da = (char*)sA + (wave * 4 + j) * 1024;
            char* db = (char*)sB + (wave * 4 + j) * 1024;
            async_copy16(da, Asrc[j] + kk);
            async_copy16(db, Bsrc[j] + kk);
        }
        __syncthreads();

        short8 a[4][2], b[4][2];
#pragma unroll
        for (int i = 0; i < 4; i++) {
            const unsigned short* ra = &sA[wm0 + i * 16 + l16][0];
            const unsigned short* rb = &sB[wn0 + i * 16 + l16][0];
            a[i][0] = *(const short8*)(ra + ca0);
            a[i][1] = *(const short8*)(ra + ca1);
            b[i][0] = *(const short8*)(rb + ca0);
            b[i][1] = *(const short8*)(rb + ca1);
        }
#pragma unroll
        for (int sub = 0; sub < 2; sub++)
#pragma unroll
            for (int mi = 0; mi < 4; mi++)
#pragma unroll
                for (int ni = 0; ni < 4; ni++)
                    acc[mi][ni] = __builtin_amdgcn_mfma_f32_16x16x32_bf16(
                        a[mi][sub], b[ni][sub], acc[mi][ni], 0, 0, 0);
        __syncthreads();
    }

    // epilogue: bias+relu; permuted-contiguous bf16 store; col-max partials (no atomics)
    const int colbase = n0 + wn0;
    float bcol[4];
#pragma unroll
    for (int ni = 0; ni < 4; ni++) bcol[ni] = bias[colbase + ni * 16 + l16];
    float cm[4] = {0.f, 0.f, 0.f, 0.f};

#pragma unroll
    for (int mi = 0; mi < 4; mi++) {
        int rowb = m0 + wm0 + mi * 16 + quad * 4;
#pragma unroll
        for (int r = 0; r < 4; r++) {
            int row = rowb + r;
            float v0 = fmaxf(acc[mi][0][r] + bcol[0], 0.f);
            float v1 = fmaxf(acc[mi][1][r] + bcol[1], 0.f);
            float v2 = fmaxf(acc[mi][2][r] + bcol[2], 0.f);
            float v3 = fmaxf(acc[mi][3][r] + bcol[3], 0.f);
            uint2 p;
            p.x = (unsigned)f2bf(v0) | ((unsigned)f2bf(v1) << 16);
            p.y = (unsigned)f2bf(v2) | ((unsigned)f2bf(v3) << 16);
            *(uint2*)(catOut + (size_t)row * K_CAT + H + colbase + l16 * 4) = p;
            bool val = row < N_NODES;
            cm[0] = fmaxf(cm[0], val ? v0 : 0.f);
            cm[1] = fmaxf(cm[1], val ? v1 : 0.f);
            cm[2] = fmaxf(cm[2], val ? v2 : 0.f);
            cm[3] = fmaxf(cm[3], val ? v3 : 0.f);
        }
    }
#pragma unroll
    for (int ni = 0; ni < 4; ni++) {
        cm[ni] = fmaxf(cm[ni], __shfl_xor(cm[ni], 16, 64));
        cm[ni] = fmaxf(cm[ni], __shfl_xor(cm[ni], 32, 64));
    }
    if (quad == 0) {
        // v_ni lives at SLOT colbase + l16*4 + ni (permuted store above), so its
        // col-max partial goes at w = l16*4 + ni. (R10 wrote ni*16+l16 -> wrong slot.)
        int cg = colbase >> 6;
        int mslot = blockIdx.x * 2 + (wave & 1);
        float* p = partial + ((size_t)cg * MAXSLOT + mslot) * 64 + l16 * 4;
#pragma unroll
        for (int ni = 0; ni < 4; ni++)
            p[ni] = cm[ni];
    }
}

// ---------------- pooling ----------------

__device__ __forceinline__ int lowerBound(const int* __restrict__ batch, int val) {
    int lo = 0, hi = N_NODES;
    while (lo < hi) {
        int mid = (lo + hi) >> 1;
        if (batch[mid] < val) lo = mid + 1; else hi = mid;
    }
    return lo;
}

__global__ void pool_partial(const unsigned short* __restrict__ cat, const int* __restrict__ batch,
                             float* __restrict__ pooled) {
    int g = blockIdx.x;
    int seg = blockIdx.y;
    int f = threadIdx.x;
    int start = lowerBound(batch, g);
    int end = lowerBound(batch, g + 1);
    int len = end - start;
    int s0 = start + (int)((long long)len * seg / 8);
    int s1 = start + (int)((long long)len * (seg + 1) / 8);
    float sum = 0.f;
    for (int n = s0; n < s1; ++n)
        sum += bf2f(cat[(size_t)n * K_CAT + H + f]);
    if (s1 > s0)
        atomicAdd(&pooled[g * H + f], sum);
}

__global__ void head_kernel(const float* __restrict__ pooled, const int* __restrict__ batch,
                            const float* __restrict__ w_out, const float* __restrict__ b_out,
                            float* __restrict__ out) {
    int g = blockIdx.x;
    int o = threadIdx.x;
    int start = lowerBound(batch, g);
    int end = lowerBound(batch, g + 1);
    float cnt = fmaxf((float)(end - start), 1.f);
    float sum = 0.f;
    for (int b = 0; b < H; ++b) {
        int f = (b & 0xC0) | ((b & 3) << 4) | ((b >> 2) & 15);
        sum += pooled[g * H + b] * w_out[f * OUT_DIM + o];
    }
    out[g * OUT_DIM + o] = b_out[o] + sum / cnt;
}

// ---------------- launch ----------------

extern "C" void kernel_launch(void* const* d_in, const int* in_sizes, int n_in,
                              void* d_out, int out_size, void* d_ws, size_t ws_size,
                              hipStream_t stream) {
    const float* x      = (const float*)d_in[0];
    const int*   ei     = (const int*)d_in[1];
    const int*   batch  = (const int*)d_in[2];
    const float* w_rel1 = (const float*)d_in[3];
    const float* w_root1= (const float*)d_in[4];
    const float* b1     = (const float*)d_in[5];
    const float* w_rel  = (const float*)d_in[6];
    const float* w_root = (const float*)d_in[7];
    const float* b      = (const float*)d_in[8];
    const float* w_out  = (const float*)d_in[9];
    const float* b_out  = (const float*)d_in[10];
    float* out = (float*)d_out;

    const int* src = ei;
    const int* dst = ei + N_EDGES;

    unsigned short* catA  = (unsigned short*)d_ws;                       // MPAD*512 bf16
    unsigned short* catB  = catA + (size_t)MPAD * K_CAT;                 // MPAD*512 bf16
    unsigned short* WcatT = catB + (size_t)MPAD * K_CAT;                 // 6*256*512 bf16
    float* agg3buf = (float*)(WcatT + (size_t)6 * H * K_CAT);            // N*4 f32
    float* pooled  = agg3buf + (size_t)N_NODES * 4;                      // G*H f32
    float* cs      = pooled + G_BATCH * H;                               // 256 f32
    float* partial = cs + H;                                             // 4*782*64 f32
    unsigned char* h8 = (unsigned char*)(partial + (size_t)4 * MAXSLOT * 64);  // N*256 u8
    int* rowptr    = (int*)(h8 + (size_t)N_NODES * H);                   // N+1
    int* degcur    = rowptr + (N_NODES + 1);                             // N
    int* blockSums = degcur + N_NODES;                                   // 256
    int* csr_src   = blockSums + SCAN_BLK;                               // E
    int* epos      = csr_src + N_EDGES;                                  // E

    // ---- build CSR ----
    hipMemsetAsync(degcur, 0, N_NODES * sizeof(int), stream);
    histo_kernel<<<(N_EDGES + 255) / 256, 256, 0, stream>>>(dst, degcur, epos);
    scan_block<<<NBLK, SCAN_BLK, 0, stream>>>(degcur, rowptr, blockSums);
    scan_finish<<<NBLK, SCAN_BLK, 0, stream>>>(rowptr, blockSums);
    fill_csr<<<(N_EDGES + 255) / 256, 256, 0, stream>>>(src, dst, rowptr, epos, csr_src);

    // ---- weights -> bf16 transposed cat (both halves slot-permuted) ----
    prep_weights<<<(6 * K_CAT * H + 255) / 256, 256, 0, stream>>>(w_rel, w_root, WcatT);

    // ---- layer 1 (3 -> 256), fp32, permuted bf16 h ----
    agg3<<<(N_NODES + 255) / 256, 256, 0, stream>>>(x, rowptr, csr_src, agg3buf);
    layer1_kernel<<<N_NODES, H, 0, stream>>>(x, agg3buf, w_rel1, w_root1, b1, catA);
    colmax_part<<<(N_NODES + 511) / 512, 256, 0, stream>>>(catA, partial);
    int nslots = ((N_NODES + 511) / 512) * 4;   // 392

    // ---- layers 2..7: reduce-scales -> quant -> int gather-agg -> MFMA (+ partials) ----
    unsigned short* cur = catA;
    unsigned short* nxt = catB;
    for (int l = 1; l <= 6; ++l) {
        reduce_cols<<<4, 1024, 0, stream>>>(partial, nslots, cs);
        quant_u8<<<(N_NODES + 3) / 4, 256, 0, stream>>>(cur, cs, h8);
        aggH<<<(N_NODES * 64 + 255) / 256, 256, 0, stream>>>(cur, h8, cs, rowptr, csr_src);
        dim3 grid(MPAD / GBM, H / GBN);
        gemm_mfma<<<grid, 256, 0, stream>>>(cur, WcatT + (size_t)(l - 1) * H * K_CAT,
                                            b + (size_t)(l - 1) * H, nxt, partial);
        nslots = (MPAD / GBM) * 2;              // 782
        unsigned short* t = cur; cur = nxt; nxt = t;
    }

    // ---- global mean pool + head ----
    hipMemsetAsync(pooled, 0, G_BATCH * H * sizeof(float), stream);
    pool_partial<<<dim3(G_BATCH, 8), 256, 0, stream>>>(cur, batch, pooled);
    head_kernel<<<G_BATCH, OUT_DIM, 0, stream>>>(pooled, batch, w_out, b_out, out);
}

// Round 12
// 749.684 us; speedup vs baseline: 1.6456x; 1.0355x over previous
//
#include <hip/hip_runtime.h>

#define N_NODES 50000
#define MPAD 50048            // 391 * 128, padded M for guard-free GEMM
#define N_EDGES 800000
#define H 256
#define K_CAT 512
#define G_BATCH 64
#define OUT_DIM 24

#define SCAN_BLK 256
#define NBLK ((N_NODES + SCAN_BLK - 1) / SCAN_BLK)   // 196
#define MAXSLOT 1564          // max partial-max slots (layer1 colmax: 1564; gemm: 782)

typedef __attribute__((ext_vector_type(8))) short short8;
typedef __attribute__((ext_vector_type(4))) float float4v;

// slot s holds feature F(s) = (s&0xC0)|((s&3)<<4)|((s>>2)&15); feature f lives at
// slot b(f) = (f&0xC0)|((f&15)<<2)|((f>>4)&3). Same permutation for u8 h8 and bf16 h.
// cs[] is indexed by SLOT. The gemm epilogue stores v_ni (logical col colbase+ni*16+l16)
// at slot colbase + l16*4 + ni, so its col-max partial uses w = l16*4 + ni.

__device__ __forceinline__ unsigned short f2bf(float f) {
    unsigned x = __float_as_uint(f);
    unsigned r = (x + 0x7FFFu + ((x >> 16) & 1u)) >> 16;   // RTNE
    return (unsigned short)r;
}
__device__ __forceinline__ float bf2f(unsigned short u) {
    return __uint_as_float(((unsigned)u) << 16);
}

__device__ __forceinline__ void async_copy16(void* lds, const void* g) {
    __builtin_amdgcn_global_load_lds(
        (const __attribute__((address_space(1))) unsigned int*)g,
        (__attribute__((address_space(3))) unsigned int*)lds, 16, 0, 0);
}

// ---------------- CSR build ----------------

__global__ void histo_kernel(const int* __restrict__ dst, int* __restrict__ deg,
                             int* __restrict__ epos) {
    int e = blockIdx.x * blockDim.x + threadIdx.x;
    if (e < N_EDGES) epos[e] = atomicAdd(&deg[dst[e]], 1);
}

__global__ void scan_block(const int* __restrict__ deg, int* __restrict__ rowptr,
                           int* __restrict__ blockSums) {
    __shared__ int s[SCAN_BLK];
    int idx = blockIdx.x * SCAN_BLK + threadIdx.x;
    int v = (idx < N_NODES) ? deg[idx] : 0;
    s[threadIdx.x] = v;
    __syncthreads();
    for (int off = 1; off < SCAN_BLK; off <<= 1) {
        int t = (threadIdx.x >= off) ? s[threadIdx.x - off] : 0;
        __syncthreads();
        s[threadIdx.x] += t;
        __syncthreads();
    }
    if (idx < N_NODES) rowptr[idx] = s[threadIdx.x] - v;
    if (threadIdx.x == SCAN_BLK - 1) blockSums[blockIdx.x] = s[threadIdx.x];
}

__global__ void scan_finish(int* __restrict__ rowptr, const int* __restrict__ blockSums) {
    __shared__ int s[SCAN_BLK];
    int t = threadIdx.x;
    int v = (t < NBLK) ? blockSums[t] : 0;
    s[t] = v;
    __syncthreads();
    for (int off = 1; off < SCAN_BLK; off <<= 1) {
        int tv = (t >= off) ? s[t - off] : 0;
        __syncthreads();
        s[t] += tv;
        __syncthreads();
    }
    int prefix = (blockIdx.x > 0) ? s[blockIdx.x - 1] : 0;
    int idx = blockIdx.x * SCAN_BLK + t;
    if (idx < N_NODES) rowptr[idx] += prefix;
    if (blockIdx.x == 0 && t == 0) rowptr[N_NODES] = s[NBLK - 1];
}

__global__ void fill_csr(const int* __restrict__ src, const int* __restrict__ dst,
                         const int* __restrict__ rowptr, const int* __restrict__ epos,
                         int* __restrict__ csr_src) {
    int e = blockIdx.x * blockDim.x + threadIdx.x;
    if (e >= N_EDGES) return;
    csr_src[rowptr[dst[e]] + epos[e]] = src[e];
}

// ---------------- weight prep (both k-halves permuted to slot order) ----------------

__global__ void prep_weights(const float* __restrict__ w_rel, const float* __restrict__ w_root,
                             unsigned short* __restrict__ WcatT) {
    int idx = blockIdx.x * blockDim.x + threadIdx.x;    // 6*512*256
    if (idx >= 6 * K_CAT * H) return;
    int n = idx & (H - 1);
    int k = (idx >> 8) & (K_CAT - 1);
    int l = idx >> 17;
    float v;
    if (k < H) {
        int f = (k & 0xC0) | ((k & 3) << 4) | ((k >> 2) & 15);
        v = w_rel[(size_t)l * H * H + f * H + n];
    } else {
        int kk = k - H;
        int f = (kk & 0xC0) | ((kk & 3) << 4) | ((kk >> 2) & 15);
        v = w_root[(size_t)l * H * H + f * H + n];
    }
    WcatT[(size_t)l * H * K_CAT + (size_t)n * K_CAT + k] = f2bf(v);
}

// ---------------- layer 1 (F_IN=3 -> H) ----------------

__global__ void agg3(const float* __restrict__ x, const int* __restrict__ rowptr,
                     const int* __restrict__ csr_src, float* __restrict__ agg) {
    int n = blockIdx.x * blockDim.x + threadIdx.x;
    if (n >= N_NODES) return;
    int beg = rowptr[n], end = rowptr[n + 1];
    float a0 = 0.f, a1 = 0.f, a2 = 0.f;
    for (int i = beg; i < end; ++i) {
        int s = csr_src[i];
        a0 += x[s * 3 + 0];
        a1 += x[s * 3 + 1];
        a2 += x[s * 3 + 2];
    }
    agg[n * 3 + 0] = a0;
    agg[n * 3 + 1] = a1;
    agg[n * 3 + 2] = a2;
}

// writes bf16 h in permuted slot order
__global__ void layer1_kernel(const float* __restrict__ x, const float* __restrict__ agg,
                              const float* __restrict__ wr, const float* __restrict__ wro,
                              const float* __restrict__ bias, unsigned short* __restrict__ cat) {
    int n = blockIdx.x;
    int f = threadIdx.x;
    float a0 = agg[n * 3 + 0], a1 = agg[n * 3 + 1], a2 = agg[n * 3 + 2];
    float x0 = x[n * 3 + 0], x1 = x[n * 3 + 1], x2 = x[n * 3 + 2];
    float v = bias[f];
    v += a0 * wr[0 * H + f] + a1 * wr[1 * H + f] + a2 * wr[2 * H + f];
    v += x0 * wro[0 * H + f] + x1 * wro[1 * H + f] + x2 * wro[2 * H + f];
    int bpos = (f & 0xC0) | ((f & 15) << 2) | ((f >> 4) & 3);
    cat[(size_t)n * K_CAT + H + bpos] = f2bf(fmaxf(v, 0.f));
}

// ---------------- per-slot column max partials of h (layer 1; atomic-free) ----------------
// 1564 slots x 32 rows; slot = blockIdx.x*4 + wave; branch-free (row clamp, dup rows are
// harmless under max); lane covers slots lane*4..+3.

__global__ __launch_bounds__(256) void colmax_part(const unsigned short* __restrict__ cat,
                                                   float* __restrict__ partial) {
    int wave = threadIdx.x >> 6, lane = threadIdx.x & 63;
    int slot = blockIdx.x * 4 + wave;
    int r0 = slot * 32;
    float m0 = 0.f, m1 = 0.f, m2 = 0.f, m3 = 0.f;
#pragma unroll 4
    for (int i = 0; i < 32; i++) {
        int r = min(r0 + i, N_NODES - 1);
        uint2 v = *(const uint2*)(cat + (size_t)r * K_CAT + H + lane * 4);
        m0 = fmaxf(m0, __uint_as_float(v.x << 16));
        m1 = fmaxf(m1, __uint_as_float(v.x & 0xffff0000u));
        m2 = fmaxf(m2, __uint_as_float(v.y << 16));
        m3 = fmaxf(m3, __uint_as_float(v.y & 0xffff0000u));
    }
    int cg = lane >> 4;
    int w = (lane * 4) & 63;
    float* p = partial + ((size_t)cg * MAXSLOT + slot) * 64 + w;
    p[0] = m0; p[1] = m1; p[2] = m2; p[3] = m3;
}

// ---------------- fold partial col-maxes -> cs[256] (grid = 4 cgs, block = 1024) ------

__global__ __launch_bounds__(1024) void reduce_cols(const float* __restrict__ partial,
                                                    int nslots, float* __restrict__ cs) {
    __shared__ float red[1024];
    int cg = blockIdx.x;
    int tid = threadIdx.x;
    int j = tid >> 6, w = tid & 63;
    float m = 0.f;
    for (int s = j; s < nslots; s += 16)
        m = fmaxf(m, partial[((size_t)cg * MAXSLOT + s) * 64 + w]);
    red[tid] = m;
    __syncthreads();
    for (int st = 8; st >= 1; st >>= 1) {
        if (j < st) red[tid] = fmaxf(red[tid], red[tid + st * 64]);
        __syncthreads();
    }
    if (j == 0) cs[cg * 64 + w] = red[tid];
}

// ---------------- quantize h (permuted bf16) -> u8 with per-slot scales ----------------

__global__ __launch_bounds__(256) void quant_u8(const unsigned short* __restrict__ cat,
                                                const float* __restrict__ cs,
                                                unsigned char* __restrict__ h8) {
    __shared__ float inv[H];
    int t = threadIdx.x;
    float c = cs[t];
    inv[t] = c > 0.f ? 255.f / c : 0.f;
    __syncthreads();
    int node = blockIdx.x * 4 + (t >> 6);
    if (node >= N_NODES) return;
    int s4 = (t & 63) * 4;
    uint2 v = *(const uint2*)(cat + (size_t)node * K_CAT + H + s4);
    float f0 = __uint_as_float(v.x << 16), f1 = __uint_as_float(v.x & 0xffff0000u);
    float f2 = __uint_as_float(v.y << 16), f3 = __uint_as_float(v.y & 0xffff0000u);
    unsigned q = (unsigned)(f0 * inv[s4] + 0.5f)
               | ((unsigned)(f1 * inv[s4 + 1] + 0.5f) << 8)
               | ((unsigned)(f2 * inv[s4 + 2] + 0.5f) << 16)
               | ((unsigned)(f3 * inv[s4 + 3] + 0.5f) << 24);
    *(unsigned*)(h8 + (size_t)node * H + s4) = q;
}

// ---------------- gather-aggregate, pure integer accumulation ----------------

__global__ __launch_bounds__(256) void aggH(unsigned short* __restrict__ cat,
                                            const unsigned char* __restrict__ h8,
                                            const float* __restrict__ cs,
                                            const int* __restrict__ rowptr,
                                            const int* __restrict__ csr_src) {
    int gtid = blockIdx.x * blockDim.x + threadIdx.x;
    int node = gtid >> 6;
    if (node >= N_NODES) return;
    int lane = threadIdx.x & 63;
    int sub = lane >> 4;
    int fl = lane & 15;
    int beg = rowptr[node], end = rowptr[node + 1];
    unsigned short* o = cat + (size_t)node * K_CAT + fl * 16;

    if (beg >= end) {
        if (sub == 0) {
            uint4 z = make_uint4(0, 0, 0, 0);
            *(uint4*)o = z;
            *(uint4*)(o + 8) = z;
        }
        return;
    }

    unsigned accE[4] = {0, 0, 0, 0}, accO[4] = {0, 0, 0, 0};
    const unsigned char* base = h8 + fl * 16;
    int last = end - 1;

    for (int i0 = beg; i0 < end; i0 += 4) {
        int idx = i0 + sub;
        int s = csr_src[idx < end ? idx : last];
        uint4 q = *(const uint4*)(base + (size_t)s * H);
        if (idx >= end) { q.x = 0u; q.y = 0u; q.z = 0u; q.w = 0u; }
        accE[0] += q.x & 0x00FF00FFu;  accO[0] += (q.x >> 8) & 0x00FF00FFu;
        accE[1] += q.y & 0x00FF00FFu;  accO[1] += (q.y >> 8) & 0x00FF00FFu;
        accE[2] += q.z & 0x00FF00FFu;  accO[2] += (q.z >> 8) & 0x00FF00FFu;
        accE[3] += q.w & 0x00FF00FFu;  accO[3] += (q.w >> 8) & 0x00FF00FFu;
    }

#pragma unroll
    for (int j = 0; j < 4; j++) {
        accE[j] += __shfl_xor(accE[j], 16, 64);
        accE[j] += __shfl_xor(accE[j], 32, 64);
        accO[j] += __shfl_xor(accO[j], 16, 64);
        accO[j] += __shfl_xor(accO[j], 32, 64);
    }
    if (sub != 0) return;

    const float k = 1.f / 255.f;
    float4 c0 = *(const float4*)(cs + fl * 16);
    float4 c1 = *(const float4*)(cs + fl * 16 + 4);
    float4 c2 = *(const float4*)(cs + fl * 16 + 8);
    float4 c3 = *(const float4*)(cs + fl * 16 + 12);
    float v0  = (float)(accE[0] & 0xFFFFu) * (c0.x * k);
    float v1  = (float)(accO[0] & 0xFFFFu) * (c0.y * k);
    float v2  = (float)(accE[0] >> 16)     * (c0.z * k);
    float v3  = (float)(accO[0] >> 16)     * (c0.w * k);
    float v4  = (float)(accE[1] & 0xFFFFu) * (c1.x * k);
    float v5  = (float)(accO[1] & 0xFFFFu) * (c1.y * k);
    float v6  = (float)(accE[1] >> 16)     * (c1.z * k);
    float v7  = (float)(accO[1] >> 16)     * (c1.w * k);
    float v8  = (float)(accE[2] & 0xFFFFu) * (c2.x * k);
    float v9  = (float)(accO[2] & 0xFFFFu) * (c2.y * k);
    float v10 = (float)(accE[2] >> 16)     * (c2.z * k);
    float v11 = (float)(accO[2] >> 16)     * (c2.w * k);
    float v12 = (float)(accE[3] & 0xFFFFu) * (c3.x * k);
    float v13 = (float)(accO[3] & 0xFFFFu) * (c3.y * k);
    float v14 = (float)(accE[3] >> 16)     * (c3.z * k);
    float v15 = (float)(accO[3] >> 16)     * (c3.w * k);

    uint4 p0, p1;
    p0.x = (unsigned)f2bf(v0)  | ((unsigned)f2bf(v1) << 16);
    p0.y = (unsigned)f2bf(v2)  | ((unsigned)f2bf(v3) << 16);
    p0.z = (unsigned)f2bf(v4)  | ((unsigned)f2bf(v5) << 16);
    p0.w = (unsigned)f2bf(v6)  | ((unsigned)f2bf(v7) << 16);
    p1.x = (unsigned)f2bf(v8)  | ((unsigned)f2bf(v9) << 16);
    p1.y = (unsigned)f2bf(v10) | ((unsigned)f2bf(v11) << 16);
    p1.z = (unsigned)f2bf(v12) | ((unsigned)f2bf(v13) << 16);
    p1.w = (unsigned)f2bf(v14) | ((unsigned)f2bf(v15) << 16);
    *(uint4*)o = p0;
    *(uint4*)(o + 8) = p1;
}

// ---------------- MFMA GEMM, GBK=64, double-buffered LDS (1 barrier/iter) ----------------

#define GBM 128
#define GBN 128
#define GBK 64
#define NITER (K_CAT / GBK)   // 8

__global__ __launch_bounds__(256) void gemm_mfma(
    const unsigned short* __restrict__ cat, const unsigned short* __restrict__ WcatT,
    const float* __restrict__ bias, unsigned short* __restrict__ catOut,
    float* __restrict__ partial) {
    __shared__ unsigned short sA[2][GBM][GBK];   // 2 x 16 KB
    __shared__ unsigned short sB[2][GBM][GBK];   // 2 x 16 KB

    const int tid = threadIdx.x;
    const int wave = tid >> 6;
    const int lane = tid & 63;
    const int quad = lane >> 4;
    const int l16 = lane & 15;
    const int wm0 = (wave & 1) * 64;
    const int wn0 = (wave >> 1) * 64;
    const int m0 = blockIdx.x * GBM;
    const int n0 = blockIdx.y * GBN;

    const int rowoff = lane >> 3;
    const int schunk = ((lane & 7) ^ rowoff) * 8;   // shorts
    const unsigned short* Asrc[4];
    const unsigned short* Bsrc[4];
#pragma unroll
    for (int j = 0; j < 4; j++) {
        int q = wave * 4 + j;
        Asrc[j] = cat + (size_t)(m0 + q * 8 + rowoff) * K_CAT + schunk;
        Bsrc[j] = WcatT + (size_t)(n0 + q * 8 + rowoff) * K_CAT + schunk;
    }

    const int sw = l16 & 7;
    const int ca0 = (quad ^ sw) * 8;
    const int ca1 = ((4 + quad) ^ sw) * 8;

    // prologue: stage iteration 0 into buffer 0
#pragma unroll
    for (int j = 0; j < 4; j++) {
        char* da = (char*)sA + (wave * 4 + j) * 1024;
        char* db = (char*)sB + (wave * 4 + j) * 1024;
        async_copy16(da, Asrc[j]);
        async_copy16(db, Bsrc[j]);
    }

    float4v acc[4][4] = {};

    for (int it = 0; it < NITER; ++it) {
        __syncthreads();   // drains stage(it); all waves done with buffer (it+1)&1
        if (it + 1 < NITER) {
            int kk = (it + 1) * GBK;
            int nb = (it + 1) & 1;
#pragma unroll
            for (int j = 0; j < 4; j++) {
                char* da = (char*)sA + nb * 16384 + (wave * 4 + j) * 1024;
                char* db = (char*)sB + nb * 16384 + (wave * 4 + j) * 1024;
                async_copy16(da, Asrc[j] + kk);
                async_copy16(db, Bsrc[j] + kk);
            }
        }
        int cb = it & 1;

        short8 a[4][2], b[4][2];
#pragma unroll
        for (int i = 0; i < 4; i++) {
            const unsigned short* ra = &sA[cb][wm0 + i * 16 + l16][0];
            const unsigned short* rb = &sB[cb][wn0 + i * 16 + l16][0];
            a[i][0] = *(const short8*)(ra + ca0);
            a[i][1] = *(const short8*)(ra + ca1);
            b[i][0] = *(const short8*)(rb + ca0);
            b[i][1] = *(const short8*)(rb + ca1);
        }
#pragma unroll
        for (int sub = 0; sub < 2; sub++)
#pragma unroll
            for (int mi = 0; mi < 4; mi++)
#pragma unroll
                for (int ni = 0; ni < 4; ni++)
                    acc[mi][ni] = __builtin_amdgcn_mfma_f32_16x16x32_bf16(
                        a[mi][sub], b[ni][sub], acc[mi][ni], 0, 0, 0);
    }

    // epilogue: bias+relu; permuted-contiguous bf16 store; col-max partials (no atomics)
    const int colbase = n0 + wn0;
    float bcol[4];
#pragma unroll
    for (int ni = 0; ni < 4; ni++) bcol[ni] = bias[colbase + ni * 16 + l16];
    float cm[4] = {0.f, 0.f, 0.f, 0.f};

#pragma unroll
    for (int mi = 0; mi < 4; mi++) {
        int rowb = m0 + wm0 + mi * 16 + quad * 4;
#pragma unroll
        for (int r = 0; r < 4; r++) {
            int row = rowb + r;
            float v0 = fmaxf(acc[mi][0][r] + bcol[0], 0.f);
            float v1 = fmaxf(acc[mi][1][r] + bcol[1], 0.f);
            float v2 = fmaxf(acc[mi][2][r] + bcol[2], 0.f);
            float v3 = fmaxf(acc[mi][3][r] + bcol[3], 0.f);
            uint2 p;
            p.x = (unsigned)f2bf(v0) | ((unsigned)f2bf(v1) << 16);
            p.y = (unsigned)f2bf(v2) | ((unsigned)f2bf(v3) << 16);
            *(uint2*)(catOut + (size_t)row * K_CAT + H + colbase + l16 * 4) = p;
            bool val = row < N_NODES;
            cm[0] = fmaxf(cm[0], val ? v0 : 0.f);
            cm[1] = fmaxf(cm[1], val ? v1 : 0.f);
            cm[2] = fmaxf(cm[2], val ? v2 : 0.f);
            cm[3] = fmaxf(cm[3], val ? v3 : 0.f);
        }
    }
#pragma unroll
    for (int ni = 0; ni < 4; ni++) {
        cm[ni] = fmaxf(cm[ni], __shfl_xor(cm[ni], 16, 64));
        cm[ni] = fmaxf(cm[ni], __shfl_xor(cm[ni], 32, 64));
    }
    if (quad == 0) {
        // v_ni lives at SLOT colbase + l16*4 + ni, so partial index is l16*4 + ni
        int cg = colbase >> 6;
        int mslot = blockIdx.x * 2 + (wave & 1);
        float* p = partial + ((size_t)cg * MAXSLOT + mslot) * 64 + l16 * 4;
#pragma unroll
        for (int ni = 0; ni < 4; ni++)
            p[ni] = cm[ni];
    }
}

// ---------------- pooling ----------------

__device__ __forceinline__ int lowerBound(const int* __restrict__ batch, int val) {
    int lo = 0, hi = N_NODES;
    while (lo < hi) {
        int mid = (lo + hi) >> 1;
        if (batch[mid] < val) lo = mid + 1; else hi = mid;
    }
    return lo;
}

__global__ void pool_partial(const unsigned short* __restrict__ cat, const int* __restrict__ batch,
                             float* __restrict__ pooled) {
    int g = blockIdx.x;
    int seg = blockIdx.y;
    int f = threadIdx.x;
    int start = lowerBound(batch, g);
    int end = lowerBound(batch, g + 1);
    int len = end - start;
    int s0 = start + (int)((long long)len * seg / 8);
    int s1 = start + (int)((long long)len * (seg + 1) / 8);
    float sum = 0.f;
    for (int n = s0; n < s1; ++n)
        sum += bf2f(cat[(size_t)n * K_CAT + H + f]);
    if (s1 > s0)
        atomicAdd(&pooled[g * H + f], sum);
}

__global__ void head_kernel(const float* __restrict__ pooled, const int* __restrict__ batch,
                            const float* __restrict__ w_out, const float* __restrict__ b_out,
                            float* __restrict__ out) {
    int g = blockIdx.x;
    int o = threadIdx.x;
    int start = lowerBound(batch, g);
    int end = lowerBound(batch, g + 1);
    float cnt = fmaxf((float)(end - start), 1.f);
    float sum = 0.f;
    for (int b = 0; b < H; ++b) {
        int f = (b & 0xC0) | ((b & 3) << 4) | ((b >> 2) & 15);
        sum += pooled[g * H + b] * w_out[f * OUT_DIM + o];
    }
    out[g * OUT_DIM + o] = b_out[o] + sum / cnt;
}

// ---------------- launch ----------------

extern "C" void kernel_launch(void* const* d_in, const int* in_sizes, int n_in,
                              void* d_out, int out_size, void* d_ws, size_t ws_size,
                              hipStream_t stream) {
    const float* x      = (const float*)d_in[0];
    const int*   ei     = (const int*)d_in[1];
    const int*   batch  = (const int*)d_in[2];
    const float* w_rel1 = (const float*)d_in[3];
    const float* w_root1= (const float*)d_in[4];
    const float* b1     = (const float*)d_in[5];
    const float* w_rel  = (const float*)d_in[6];
    const float* w_root = (const float*)d_in[7];
    const float* b      = (const float*)d_in[8];
    const float* w_out  = (const float*)d_in[9];
    const float* b_out  = (const float*)d_in[10];
    float* out = (float*)d_out;

    const int* src = ei;
    const int* dst = ei + N_EDGES;

    unsigned short* catA  = (unsigned short*)d_ws;                       // MPAD*512 bf16
    unsigned short* catB  = catA + (size_t)MPAD * K_CAT;                 // MPAD*512 bf16
    unsigned short* WcatT = catB + (size_t)MPAD * K_CAT;                 // 6*256*512 bf16
    float* agg3buf = (float*)(WcatT + (size_t)6 * H * K_CAT);            // N*4 f32
    float* pooled  = agg3buf + (size_t)N_NODES * 4;                      // G*H f32
    float* cs      = pooled + G_BATCH * H;                               // 256 f32
    float* partial = cs + H;                                             // 4*MAXSLOT*64 f32
    unsigned char* h8 = (unsigned char*)(partial + (size_t)4 * MAXSLOT * 64);  // N*256 u8
    int* rowptr    = (int*)(h8 + (size_t)N_NODES * H);                   // N+1
    int* degcur    = rowptr + (N_NODES + 1);                             // N
    int* blockSums = degcur + N_NODES;                                   // 256
    int* csr_src   = blockSums + SCAN_BLK;                               // E
    int* epos      = csr_src + N_EDGES;                                  // E

    // ---- build CSR ----
    hipMemsetAsync(degcur, 0, N_NODES * sizeof(int), stream);
    histo_kernel<<<(N_EDGES + 255) / 256, 256, 0, stream>>>(dst, degcur, epos);
    scan_block<<<NBLK, SCAN_BLK, 0, stream>>>(degcur, rowptr, blockSums);
    scan_finish<<<NBLK, SCAN_BLK, 0, stream>>>(rowptr, blockSums);
    fill_csr<<<(N_EDGES + 255) / 256, 256, 0, stream>>>(src, dst, rowptr, epos, csr_src);

    // ---- weights -> bf16 transposed cat (both halves slot-permuted) ----
    prep_weights<<<(6 * K_CAT * H + 255) / 256, 256, 0, stream>>>(w_rel, w_root, WcatT);

    // ---- layer 1 (3 -> 256), fp32, permuted bf16 h ----
    agg3<<<(N_NODES + 255) / 256, 256, 0, stream>>>(x, rowptr, csr_src, agg3buf);
    layer1_kernel<<<N_NODES, H, 0, stream>>>(x, agg3buf, w_rel1, w_root1, b1, catA);
    colmax_part<<<(N_NODES + 127) / 128, 256, 0, stream>>>(catA, partial);
    int nslots = ((N_NODES + 127) / 128) * 4;   // 1564

    // ---- layers 2..7: reduce-scales -> quant -> int gather-agg -> MFMA (+ partials) ----
    unsigned short* cur = catA;
    unsigned short* nxt = catB;
    for (int l = 1; l <= 6; ++l) {
        reduce_cols<<<4, 1024, 0, stream>>>(partial, nslots, cs);
        quant_u8<<<(N_NODES + 3) / 4, 256, 0, stream>>>(cur, cs, h8);
        aggH<<<(N_NODES * 64 + 255) / 256, 256, 0, stream>>>(cur, h8, cs, rowptr, csr_src);
        dim3 grid(MPAD / GBM, H / GBN);
        gemm_mfma<<<grid, 256, 0, stream>>>(cur, WcatT + (size_t)(l - 1) * H * K_CAT,
                                            b + (size_t)(l - 1) * H, nxt, partial);
        nslots = (MPAD / GBM) * 2;              // 782
        unsigned short* t = cur; cur = nxt; nxt = t;
    }

    // ---- global mean pool + head ----
    hipMemsetAsync(pooled, 0, G_BATCH * H * sizeof(float), stream);
    pool_partial<<<dim3(G_BATCH, 8), 256, 0, stream>>>(cur, batch, pooled);
    head_kernel<<<G_BATCH, OUT_DIM, 0, stream>>>(pooled, batch, w_out, b_out, out);
}

// Round 13
// 741.782 us; speedup vs baseline: 1.6631x; 1.0107x over previous
//
#include <hip/hip_runtime.h>

#define N_NODES 50000
#define MPAD 50048            // 391 * 128, padded M for guard-free GEMM
#define N_EDGES 800000
#define H 256
#define K_CAT 512
#define G_BATCH 64
#define OUT_DIM 24

#define SCAN_BLK 256
#define NBLK ((N_NODES + SCAN_BLK - 1) / SCAN_BLK)   // 196
#define MAXSLOT 1564          // max partial-max slots (layer1 colmax: 1564; gemm: 782)

typedef __attribute__((ext_vector_type(8))) short short8;
typedef __attribute__((ext_vector_type(4))) float float4v;

// slot s holds feature F(s) = (s&0xC0)|((s&3)<<4)|((s>>2)&15); feature f lives at
// slot b(f) = (f&0xC0)|((f&15)<<2)|((f>>4)&3). Same permutation for u8 h8 and bf16 h.
// cs[] is indexed by SLOT. The gemm epilogue stores v_ni (logical col colbase+ni*16+l16)
// at slot colbase + l16*4 + ni, so its col-max partial uses w = l16*4 + ni.

__device__ __forceinline__ unsigned short f2bf(float f) {
    unsigned x = __float_as_uint(f);
    unsigned r = (x + 0x7FFFu + ((x >> 16) & 1u)) >> 16;   // RTNE
    return (unsigned short)r;
}
__device__ __forceinline__ float bf2f(unsigned short u) {
    return __uint_as_float(((unsigned)u) << 16);
}

__device__ __forceinline__ void async_copy16(void* lds, const void* g) {
    __builtin_amdgcn_global_load_lds(
        (const __attribute__((address_space(1))) unsigned int*)g,
        (__attribute__((address_space(3))) unsigned int*)lds, 16, 0, 0);
}

// odd-byte extract: (q>>8) & 0x00FF00FF in one v_perm_b32
__device__ __forceinline__ unsigned oddb(unsigned q) {
    return __builtin_amdgcn_perm(0u, q, 0x0C030C01u);
}

// ---------------- CSR build ----------------

__global__ void histo_kernel(const int* __restrict__ dst, int* __restrict__ deg,
                             int* __restrict__ epos) {
    int e = blockIdx.x * blockDim.x + threadIdx.x;
    if (e < N_EDGES) epos[e] = atomicAdd(&deg[dst[e]], 1);
}

__global__ void scan_block(const int* __restrict__ deg, int* __restrict__ rowptr,
                           int* __restrict__ blockSums) {
    __shared__ int s[SCAN_BLK];
    int idx = blockIdx.x * SCAN_BLK + threadIdx.x;
    int v = (idx < N_NODES) ? deg[idx] : 0;
    s[threadIdx.x] = v;
    __syncthreads();
    for (int off = 1; off < SCAN_BLK; off <<= 1) {
        int t = (threadIdx.x >= off) ? s[threadIdx.x - off] : 0;
        __syncthreads();
        s[threadIdx.x] += t;
        __syncthreads();
    }
    if (idx < N_NODES) rowptr[idx] = s[threadIdx.x] - v;
    if (threadIdx.x == SCAN_BLK - 1) blockSums[blockIdx.x] = s[threadIdx.x];
}

__global__ void scan_finish(int* __restrict__ rowptr, const int* __restrict__ blockSums) {
    __shared__ int s[SCAN_BLK];
    int t = threadIdx.x;
    int v = (t < NBLK) ? blockSums[t] : 0;
    s[t] = v;
    __syncthreads();
    for (int off = 1; off < SCAN_BLK; off <<= 1) {
        int tv = (t >= off) ? s[t - off] : 0;
        __syncthreads();
        s[t] += tv;
        __syncthreads();
    }
    int prefix = (blockIdx.x > 0) ? s[blockIdx.x - 1] : 0;
    int idx = blockIdx.x * SCAN_BLK + t;
    if (idx < N_NODES) rowptr[idx] += prefix;
    if (blockIdx.x == 0 && t == 0) rowptr[N_NODES] = s[NBLK - 1];
}

__global__ void fill_csr(const int* __restrict__ src, const int* __restrict__ dst,
                         const int* __restrict__ rowptr, const int* __restrict__ epos,
                         int* __restrict__ csr_src) {
    int e = blockIdx.x * blockDim.x + threadIdx.x;
    if (e >= N_EDGES) return;
    csr_src[rowptr[dst[e]] + epos[e]] = src[e];
}

// ---------------- weight prep (both k-halves permuted to slot order) ----------------

__global__ void prep_weights(const float* __restrict__ w_rel, const float* __restrict__ w_root,
                             unsigned short* __restrict__ WcatT) {
    int idx = blockIdx.x * blockDim.x + threadIdx.x;    // 6*512*256
    if (idx >= 6 * K_CAT * H) return;
    int n = idx & (H - 1);
    int k = (idx >> 8) & (K_CAT - 1);
    int l = idx >> 17;
    float v;
    if (k < H) {
        int f = (k & 0xC0) | ((k & 3) << 4) | ((k >> 2) & 15);
        v = w_rel[(size_t)l * H * H + f * H + n];
    } else {
        int kk = k - H;
        int f = (kk & 0xC0) | ((kk & 3) << 4) | ((kk >> 2) & 15);
        v = w_root[(size_t)l * H * H + f * H + n];
    }
    WcatT[(size_t)l * H * K_CAT + (size_t)n * K_CAT + k] = f2bf(v);
}

// ---------------- layer 1 (F_IN=3 -> H) ----------------

__global__ void agg3(const float* __restrict__ x, const int* __restrict__ rowptr,
                     const int* __restrict__ csr_src, float* __restrict__ agg) {
    int n = blockIdx.x * blockDim.x + threadIdx.x;
    if (n >= N_NODES) return;
    int beg = rowptr[n], end = rowptr[n + 1];
    float a0 = 0.f, a1 = 0.f, a2 = 0.f;
    for (int i = beg; i < end; ++i) {
        int s = csr_src[i];
        a0 += x[s * 3 + 0];
        a1 += x[s * 3 + 1];
        a2 += x[s * 3 + 2];
    }
    agg[n * 3 + 0] = a0;
    agg[n * 3 + 1] = a1;
    agg[n * 3 + 2] = a2;
}

// writes bf16 h in permuted slot order
__global__ void layer1_kernel(const float* __restrict__ x, const float* __restrict__ agg,
                              const float* __restrict__ wr, const float* __restrict__ wro,
                              const float* __restrict__ bias, unsigned short* __restrict__ cat) {
    int n = blockIdx.x;
    int f = threadIdx.x;
    float a0 = agg[n * 3 + 0], a1 = agg[n * 3 + 1], a2 = agg[n * 3 + 2];
    float x0 = x[n * 3 + 0], x1 = x[n * 3 + 1], x2 = x[n * 3 + 2];
    float v = bias[f];
    v += a0 * wr[0 * H + f] + a1 * wr[1 * H + f] + a2 * wr[2 * H + f];
    v += x0 * wro[0 * H + f] + x1 * wro[1 * H + f] + x2 * wro[2 * H + f];
    int bpos = (f & 0xC0) | ((f & 15) << 2) | ((f >> 4) & 3);
    cat[(size_t)n * K_CAT + H + bpos] = f2bf(fmaxf(v, 0.f));
}

// ---------------- per-slot column max partials of h (layer 1; atomic-free) ----------------

__global__ __launch_bounds__(256) void colmax_part(const unsigned short* __restrict__ cat,
                                                   float* __restrict__ partial) {
    int wave = threadIdx.x >> 6, lane = threadIdx.x & 63;
    int slot = blockIdx.x * 4 + wave;
    int r0 = slot * 32;
    float m0 = 0.f, m1 = 0.f, m2 = 0.f, m3 = 0.f;
#pragma unroll 4
    for (int i = 0; i < 32; i++) {
        int r = min(r0 + i, N_NODES - 1);
        uint2 v = *(const uint2*)(cat + (size_t)r * K_CAT + H + lane * 4);
        m0 = fmaxf(m0, __uint_as_float(v.x << 16));
        m1 = fmaxf(m1, __uint_as_float(v.x & 0xffff0000u));
        m2 = fmaxf(m2, __uint_as_float(v.y << 16));
        m3 = fmaxf(m3, __uint_as_float(v.y & 0xffff0000u));
    }
    int cg = lane >> 4;
    int w = (lane * 4) & 63;
    float* p = partial + ((size_t)cg * MAXSLOT + slot) * 64 + w;
    p[0] = m0; p[1] = m1; p[2] = m2; p[3] = m3;
}

// ---------------- fold partial col-maxes -> cs[256] (grid = 4 cgs, block = 1024) ------

__global__ __launch_bounds__(1024) void reduce_cols(const float* __restrict__ partial,
                                                    int nslots, float* __restrict__ cs) {
    __shared__ float red[1024];
    int cg = blockIdx.x;
    int tid = threadIdx.x;
    int j = tid >> 6, w = tid & 63;
    float m = 0.f;
    for (int s = j; s < nslots; s += 16)
        m = fmaxf(m, partial[((size_t)cg * MAXSLOT + s) * 64 + w]);
    red[tid] = m;
    __syncthreads();
    for (int st = 8; st >= 1; st >>= 1) {
        if (j < st) red[tid] = fmaxf(red[tid], red[tid + st * 64]);
        __syncthreads();
    }
    if (j == 0) cs[cg * 64 + w] = red[tid];
}

// ---------------- quantize h (permuted bf16) -> u8, 16 B/thread, 8 nodes/block --------

__global__ __launch_bounds__(256) void quant_u8(const unsigned short* __restrict__ cat,
                                                const float* __restrict__ cs,
                                                unsigned char* __restrict__ h8) {
    __shared__ float inv[H];
    int t = threadIdx.x;
    float c = cs[t];
    inv[t] = c > 0.f ? 255.f / c : 0.f;
    __syncthreads();
    int node = blockIdx.x * 8 + (t >> 5);
    if (node >= N_NODES) return;
    int s8 = (t & 31) * 8;
    uint4 v = *(const uint4*)(cat + (size_t)node * K_CAT + H + s8);
    float f0 = __uint_as_float(v.x << 16), f1 = __uint_as_float(v.x & 0xffff0000u);
    float f2 = __uint_as_float(v.y << 16), f3 = __uint_as_float(v.y & 0xffff0000u);
    float f4 = __uint_as_float(v.z << 16), f5 = __uint_as_float(v.z & 0xffff0000u);
    float f6 = __uint_as_float(v.w << 16), f7 = __uint_as_float(v.w & 0xffff0000u);
    uint2 q;
    q.x = (unsigned)(f0 * inv[s8] + 0.5f)
        | ((unsigned)(f1 * inv[s8 + 1] + 0.5f) << 8)
        | ((unsigned)(f2 * inv[s8 + 2] + 0.5f) << 16)
        | ((unsigned)(f3 * inv[s8 + 3] + 0.5f) << 24);
    q.y = (unsigned)(f4 * inv[s8 + 4] + 0.5f)
        | ((unsigned)(f5 * inv[s8 + 5] + 0.5f) << 8)
        | ((unsigned)(f6 * inv[s8 + 6] + 0.5f) << 16)
        | ((unsigned)(f7 * inv[s8 + 7] + 0.5f) << 24);
    *(uint2*)(h8 + (size_t)node * H + s8) = q;
}

// ---------------- gather-aggregate, pure integer accumulation (perm unpack) ------------

__global__ __launch_bounds__(256) void aggH(unsigned short* __restrict__ cat,
                                            const unsigned char* __restrict__ h8,
                                            const float* __restrict__ cs,
                                            const int* __restrict__ rowptr,
                                            const int* __restrict__ csr_src) {
    int gtid = blockIdx.x * blockDim.x + threadIdx.x;
    int node = gtid >> 6;
    if (node >= N_NODES) return;
    int lane = threadIdx.x & 63;
    int sub = lane >> 4;
    int fl = lane & 15;
    int beg = rowptr[node], end = rowptr[node + 1];
    unsigned short* o = cat + (size_t)node * K_CAT + fl * 16;

    if (beg >= end) {
        if (sub == 0) {
            uint4 z = make_uint4(0, 0, 0, 0);
            *(uint4*)o = z;
            *(uint4*)(o + 8) = z;
        }
        return;
    }

    unsigned accE[4] = {0, 0, 0, 0}, accO[4] = {0, 0, 0, 0};
    const unsigned char* base = h8 + fl * 16;
    int last = end - 1;

    for (int i0 = beg; i0 < end; i0 += 4) {
        int idx = i0 + sub;
        int s = csr_src[idx < end ? idx : last];
        uint4 q = *(const uint4*)(base + (size_t)s * H);
        if (idx >= end) { q.x = 0u; q.y = 0u; q.z = 0u; q.w = 0u; }
        accE[0] += q.x & 0x00FF00FFu;  accO[0] += oddb(q.x);
        accE[1] += q.y & 0x00FF00FFu;  accO[1] += oddb(q.y);
        accE[2] += q.z & 0x00FF00FFu;  accO[2] += oddb(q.z);
        accE[3] += q.w & 0x00FF00FFu;  accO[3] += oddb(q.w);
    }

#pragma unroll
    for (int j = 0; j < 4; j++) {
        accE[j] += __shfl_xor(accE[j], 16, 64);
        accE[j] += __shfl_xor(accE[j], 32, 64);
        accO[j] += __shfl_xor(accO[j], 16, 64);
        accO[j] += __shfl_xor(accO[j], 32, 64);
    }
    if (sub != 0) return;

    const float k = 1.f / 255.f;
    float4 c0 = *(const float4*)(cs + fl * 16);
    float4 c1 = *(const float4*)(cs + fl * 16 + 4);
    float4 c2 = *(const float4*)(cs + fl * 16 + 8);
    float4 c3 = *(const float4*)(cs + fl * 16 + 12);
    float v0  = (float)(accE[0] & 0xFFFFu) * (c0.x * k);
    float v1  = (float)(accO[0] & 0xFFFFu) * (c0.y * k);
    float v2  = (float)(accE[0] >> 16)     * (c0.z * k);
    float v3  = (float)(accO[0] >> 16)     * (c0.w * k);
    float v4  = (float)(accE[1] & 0xFFFFu) * (c1.x * k);
    float v5  = (float)(accO[1] & 0xFFFFu) * (c1.y * k);
    float v6  = (float)(accE[1] >> 16)     * (c1.z * k);
    float v7  = (float)(accO[1] >> 16)     * (c1.w * k);
    float v8  = (float)(accE[2] & 0xFFFFu) * (c2.x * k);
    float v9  = (float)(accO[2] & 0xFFFFu) * (c2.y * k);
    float v10 = (float)(accE[2] >> 16)     * (c2.z * k);
    float v11 = (float)(accO[2] >> 16)     * (c2.w * k);
    float v12 = (float)(accE[3] & 0xFFFFu) * (c3.x * k);
    float v13 = (float)(accO[3] & 0xFFFFu) * (c3.y * k);
    float v14 = (float)(accE[3] >> 16)     * (c3.z * k);
    float v15 = (float)(accO[3] >> 16)     * (c3.w * k);

    uint4 p0, p1;
    p0.x = (unsigned)f2bf(v0)  | ((unsigned)f2bf(v1) << 16);
    p0.y = (unsigned)f2bf(v2)  | ((unsigned)f2bf(v3) << 16);
    p0.z = (unsigned)f2bf(v4)  | ((unsigned)f2bf(v5) << 16);
    p0.w = (unsigned)f2bf(v6)  | ((unsigned)f2bf(v7) << 16);
    p1.x = (unsigned)f2bf(v8)  | ((unsigned)f2bf(v9) << 16);
    p1.y = (unsigned)f2bf(v10) | ((unsigned)f2bf(v11) << 16);
    p1.z = (unsigned)f2bf(v12) | ((unsigned)f2bf(v13) << 16);
    p1.w = (unsigned)f2bf(v14) | ((unsigned)f2bf(v15) << 16);
    *(uint4*)o = p0;
    *(uint4*)(o + 8) = p1;
}

// ---------------- MFMA GEMM, GBK=64, double-buffered LDS, paired n-blocks --------------
// grid = dim3(2, 391): the two n-blocks sharing an A m-tile are dispatch-adjacent,
// so the second read of the A tile hits L2/LLC instead of streaming HBM twice.

#define GBM 128
#define GBN 128
#define GBK 64
#define NITER (K_CAT / GBK)   // 8

__global__ __launch_bounds__(256) void gemm_mfma(
    const unsigned short* __restrict__ cat, const unsigned short* __restrict__ WcatT,
    const float* __restrict__ bias, unsigned short* __restrict__ catOut,
    float* __restrict__ partial) {
    __shared__ unsigned short sA[2][GBM][GBK];   // 2 x 16 KB
    __shared__ unsigned short sB[2][GBM][GBK];   // 2 x 16 KB

    const int tid = threadIdx.x;
    const int wave = tid >> 6;
    const int lane = tid & 63;
    const int quad = lane >> 4;
    const int l16 = lane & 15;
    const int wm0 = (wave & 1) * 64;
    const int wn0 = (wave >> 1) * 64;
    const int m0 = blockIdx.y * GBM;
    const int n0 = blockIdx.x * GBN;

    const int rowoff = lane >> 3;
    const int schunk = ((lane & 7) ^ rowoff) * 8;   // shorts
    const unsigned short* Asrc[4];
    const unsigned short* Bsrc[4];
#pragma unroll
    for (int j = 0; j < 4; j++) {
        int q = wave * 4 + j;
        Asrc[j] = cat + (size_t)(m0 + q * 8 + rowoff) * K_CAT + schunk;
        Bsrc[j] = WcatT + (size_t)(n0 + q * 8 + rowoff) * K_CAT + schunk;
    }

    const int sw = l16 & 7;
    const int ca0 = (quad ^ sw) * 8;
    const int ca1 = ((4 + quad) ^ sw) * 8;

    // prologue: stage iteration 0 into buffer 0
#pragma unroll
    for (int j = 0; j < 4; j++) {
        char* da = (char*)sA + (wave * 4 + j) * 1024;
        char* db = (char*)sB + (wave * 4 + j) * 1024;
        async_copy16(da, Asrc[j]);
        async_copy16(db, Bsrc[j]);
    }

    float4v acc[4][4] = {};

    for (int it = 0; it < NITER; ++it) {
        __syncthreads();
        if (it + 1 < NITER) {
            int kk = (it + 1) * GBK;
            int nb = (it + 1) & 1;
#pragma unroll
            for (int j = 0; j < 4; j++) {
                char* da = (char*)sA + nb * 16384 + (wave * 4 + j) * 1024;
                char* db = (char*)sB + nb * 16384 + (wave * 4 + j) * 1024;
                async_copy16(da, Asrc[j] + kk);
                async_copy16(db, Bsrc[j] + kk);
            }
        }
        int cb = it & 1;

        short8 a[4][2], b[4][2];
#pragma unroll
        for (int i = 0; i < 4; i++) {
            const unsigned short* ra = &sA[cb][wm0 + i * 16 + l16][0];
            const unsigned short* rb = &sB[cb][wn0 + i * 16 + l16][0];
            a[i][0] = *(const short8*)(ra + ca0);
            a[i][1] = *(const short8*)(ra + ca1);
            b[i][0] = *(const short8*)(rb + ca0);
            b[i][1] = *(const short8*)(rb + ca1);
        }
#pragma unroll
        for (int sub = 0; sub < 2; sub++)
#pragma unroll
            for (int mi = 0; mi < 4; mi++)
#pragma unroll
                for (int ni = 0; ni < 4; ni++)
                    acc[mi][ni] = __builtin_amdgcn_mfma_f32_16x16x32_bf16(
                        a[mi][sub], b[ni][sub], acc[mi][ni], 0, 0, 0);
    }

    // epilogue: bias+relu; permuted-contiguous bf16 store; col-max partials (no atomics)
    const int colbase = n0 + wn0;
    float bcol[4];
#pragma unroll
    for (int ni = 0; ni < 4; ni++) bcol[ni] = bias[colbase + ni * 16 + l16];
    float cm[4] = {0.f, 0.f, 0.f, 0.f};

#pragma unroll
    for (int mi = 0; mi < 4; mi++) {
        int rowb = m0 + wm0 + mi * 16 + quad * 4;
#pragma unroll
        for (int r = 0; r < 4; r++) {
            int row = rowb + r;
            float v0 = fmaxf(acc[mi][0][r] + bcol[0], 0.f);
            float v1 = fmaxf(acc[mi][1][r] + bcol[1], 0.f);
            float v2 = fmaxf(acc[mi][2][r] + bcol[2], 0.f);
            float v3 = fmaxf(acc[mi][3][r] + bcol[3], 0.f);
            uint2 p;
            p.x = (unsigned)f2bf(v0) | ((unsigned)f2bf(v1) << 16);
            p.y = (unsigned)f2bf(v2) | ((unsigned)f2bf(v3) << 16);
            *(uint2*)(catOut + (size_t)row * K_CAT + H + colbase + l16 * 4) = p;
            bool val = row < N_NODES;
            cm[0] = fmaxf(cm[0], val ? v0 : 0.f);
            cm[1] = fmaxf(cm[1], val ? v1 : 0.f);
            cm[2] = fmaxf(cm[2], val ? v2 : 0.f);
            cm[3] = fmaxf(cm[3], val ? v3 : 0.f);
        }
    }
#pragma unroll
    for (int ni = 0; ni < 4; ni++) {
        cm[ni] = fmaxf(cm[ni], __shfl_xor(cm[ni], 16, 64));
        cm[ni] = fmaxf(cm[ni], __shfl_xor(cm[ni], 32, 64));
    }
    if (quad == 0) {
        int cg = colbase >> 6;
        int mslot = blockIdx.y * 2 + (wave & 1);
        float* p = partial + ((size_t)cg * MAXSLOT + mslot) * 64 + l16 * 4;
#pragma unroll
        for (int ni = 0; ni < 4; ni++)
            p[ni] = cm[ni];
    }
}

// ---------------- pooling ----------------

__device__ __forceinline__ int lowerBound(const int* __restrict__ batch, int val) {
    int lo = 0, hi = N_NODES;
    while (lo < hi) {
        int mid = (lo + hi) >> 1;
        if (batch[mid] < val) lo = mid + 1; else hi = mid;
    }
    return lo;
}

__global__ void pool_partial(const unsigned short* __restrict__ cat, const int* __restrict__ batch,
                             float* __restrict__ pooled) {
    int g = blockIdx.x;
    int seg = blockIdx.y;
    int f = threadIdx.x;
    int start = lowerBound(batch, g);
    int end = lowerBound(batch, g + 1);
    int len = end - start;
    int s0 = start + (int)((long long)len * seg / 8);
    int s1 = start + (int)((long long)len * (seg + 1) / 8);
    float sum = 0.f;
    for (int n = s0; n < s1; ++n)
        sum += bf2f(cat[(size_t)n * K_CAT + H + f]);
    if (s1 > s0)
        atomicAdd(&pooled[g * H + f], sum);
}

__global__ void head_kernel(const float* __restrict__ pooled, const int* __restrict__ batch,
                            const float* __restrict__ w_out, const float* __restrict__ b_out,
                            float* __restrict__ out) {
    int g = blockIdx.x;
    int o = threadIdx.x;
    int start = lowerBound(batch, g);
    int end = lowerBound(batch, g + 1);
    float cnt = fmaxf((float)(end - start), 1.f);
    float sum = 0.f;
    for (int b = 0; b < H; ++b) {
        int f = (b & 0xC0) | ((b & 3) << 4) | ((b >> 2) & 15);
        sum += pooled[g * H + b] * w_out[f * OUT_DIM + o];
    }
    out[g * OUT_DIM + o] = b_out[o] + sum / cnt;
}

// ---------------- launch ----------------

extern "C" void kernel_launch(void* const* d_in, const int* in_sizes, int n_in,
                              void* d_out, int out_size, void* d_ws, size_t ws_size,
                              hipStream_t stream) {
    const float* x      = (const float*)d_in[0];
    const int*   ei     = (const int*)d_in[1];
    const int*   batch  = (const int*)d_in[2];
    const float* w_rel1 = (const float*)d_in[3];
    const float* w_root1= (const float*)d_in[4];
    const float* b1     = (const float*)d_in[5];
    const float* w_rel  = (const float*)d_in[6];
    const float* w_root = (const float*)d_in[7];
    const float* b      = (const float*)d_in[8];
    const float* w_out  = (const float*)d_in[9];
    const float* b_out  = (const float*)d_in[10];
    float* out = (float*)d_out;

    const int* src = ei;
    const int* dst = ei + N_EDGES;

    unsigned short* catA  = (unsigned short*)d_ws;                       // MPAD*512 bf16
    unsigned short* catB  = catA + (size_t)MPAD * K_CAT;                 // MPAD*512 bf16
    unsigned short* WcatT = catB + (size_t)MPAD * K_CAT;                 // 6*256*512 bf16
    float* agg3buf = (float*)(WcatT + (size_t)6 * H * K_CAT);            // N*4 f32
    float* pooled  = agg3buf + (size_t)N_NODES * 4;                      // G*H f32
    float* cs      = pooled + G_BATCH * H;                               // 256 f32
    float* partial = cs + H;                                             // 4*MAXSLOT*64 f32
    unsigned char* h8 = (unsigned char*)(partial + (size_t)4 * MAXSLOT * 64);  // N*256 u8
    int* rowptr    = (int*)(h8 + (size_t)N_NODES * H);                   // N+1
    int* degcur    = rowptr + (N_NODES + 1);                             // N
    int* blockSums = degcur + N_NODES;                                   // 256
    int* csr_src   = blockSums + SCAN_BLK;                               // E
    int* epos      = csr_src + N_EDGES;                                  // E

    // ---- build CSR ----
    hipMemsetAsync(degcur, 0, N_NODES * sizeof(int), stream);
    histo_kernel<<<(N_EDGES + 255) / 256, 256, 0, stream>>>(dst, degcur, epos);
    scan_block<<<NBLK, SCAN_BLK, 0, stream>>>(degcur, rowptr, blockSums);
    scan_finish<<<NBLK, SCAN_BLK, 0, stream>>>(rowptr, blockSums);
    fill_csr<<<(N_EDGES + 255) / 256, 256, 0, stream>>>(src, dst, rowptr, epos, csr_src);

    // ---- weights -> bf16 transposed cat (both halves slot-permuted) ----
    prep_weights<<<(6 * K_CAT * H + 255) / 256, 256, 0, stream>>>(w_rel, w_root, WcatT);

    // ---- layer 1 (3 -> 256), fp32, permuted bf16 h ----
    agg3<<<(N_NODES + 255) / 256, 256, 0, stream>>>(x, rowptr, csr_src, agg3buf);
    layer1_kernel<<<N_NODES, H, 0, stream>>>(x, agg3buf, w_rel1, w_root1, b1, catA);
    colmax_part<<<(N_NODES + 127) / 128, 256, 0, stream>>>(catA, partial);
    int nslots = ((N_NODES + 127) / 128) * 4;   // 1564

    // ---- layers 2..7: reduce-scales -> quant -> int gather-agg -> MFMA (+ partials) ----
    unsigned short* cur = catA;
    unsigned short* nxt = catB;
    for (int l = 1; l <= 6; ++l) {
        reduce_cols<<<4, 1024, 0, stream>>>(partial, nslots, cs);
        quant_u8<<<(N_NODES + 7) / 8, 256, 0, stream>>>(cur, cs, h8);
        aggH<<<(N_NODES * 64 + 255) / 256, 256, 0, stream>>>(cur, h8, cs, rowptr, csr_src);
        dim3 grid(H / GBN, MPAD / GBM);
        gemm_mfma<<<grid, 256, 0, stream>>>(cur, WcatT + (size_t)(l - 1) * H * K_CAT,
                                            b + (size_t)(l - 1) * H, nxt, partial);
        nslots = (MPAD / GBM) * 2;              // 782
        unsigned short* t = cur; cur = nxt; nxt = t;
    }

    // ---- global mean pool + head ----
    hipMemsetAsync(pooled, 0, G_BATCH * H * sizeof(float), stream);
    pool_partial<<<dim3(G_BATCH, 8), 256, 0, stream>>>(cur, batch, pooled);
    head_kernel<<<G_BATCH, OUT_DIM, 0, stream>>>(pooled, batch, w_out, b_out, out);
}